// Round 23
// baseline (724.681 us; speedup 1.0000x reference)
//
#include <hip/hip_runtime.h>
#include <hip/hip_bf16.h>
#include <math.h>

// ---------------- problem constants ----------------
#define QLEN 256
#define MLEN 256
#define KLEN 512
#define BSZ 8
#define DMODEL 1024
#define NHEAD 16
#define DHEAD 64
#define DINNER 4096
#define NTOKEN 32000
#define NLAYER 2
#define NTOK 2048          // QLEN*BSZ
#define VTILES 250         // 32000/128
#define LPAD 40            // reg-staged LDS row pitch (R3-proven)

typedef __attribute__((ext_vector_type(8))) short bf16x8;
typedef __attribute__((ext_vector_type(4))) float f32x4;

__device__ __forceinline__ float b2f(ushort u) { return __uint_as_float(((unsigned)u) << 16); }
__device__ __forceinline__ ushort f2b(float x) {
  unsigned u = __float_as_uint(x);
  return (ushort)((u + 0x7fffu + ((u >> 16) & 1u)) >> 16);
}

// pack 8 f32 -> 8 bf16 (same rounding as convert_bf16 did)
__device__ __forceinline__ bf16x8 pack8(float4 x, float4 y) {
    bf16x8 r;
    r[0] = (short)f2b(x.x); r[1] = (short)f2b(x.y);
    r[2] = (short)f2b(x.z); r[3] = (short)f2b(x.w);
    r[4] = (short)f2b(y.x); r[5] = (short)f2b(y.y);
    r[6] = (short)f2b(y.z); r[7] = (short)f2b(y.w);
    return r;
}

// async global->LDS, 16B per lane. lds ptr must be wave-uniform base; HW adds lane*16.
__device__ __forceinline__ void gload16(const ushort* g, ushort* l) {
    __builtin_amdgcn_global_load_lds(
        (const __attribute__((address_space(1))) unsigned int*)(g),
        (__attribute__((address_space(3))) unsigned int*)(l), 16, 0, 0);
}

// ---------------- workspace layout (float offsets) ----------------
static const size_t O_H      = 0;                    // h fp32          2,097,152
static const size_t O_HBF    = 2097152;              // h bf16          1,048,576
static const size_t O_POSBF  = 3145728;              // pos bf16          262,144
static const size_t O_QKVT   = 3407872;              // 2x 3072x1024 bf 3,145,728
static const size_t O_RWT    = O_QKVT + 3145728;     // 2x 1024x1024 bf 1,048,576
static const size_t O_OWT    = O_RWT + 1048576;      // 2x 1024x1024 bf 1,048,576
static const size_t O_FFW1T  = O_OWT + 1048576;      // 2x 4096x1024 bf 4,194,304
static const size_t O_FFW2T  = O_FFW1T + 4194304;    // 2x 1024x4096 bf 4,194,304
static const size_t O_SCR    = O_FFW2T + 4194304;    // = 17,039,360
static const size_t O_MEMBF  = O_SCR;                // 2x 2048x1024 bf 2,097,152
static const size_t O_QW     = O_SCR + 2097152;      // 8*16*256*64 bf  1,048,576
static const size_t O_QR     = O_QW + 1048576;       //                 1,048,576
static const size_t O_KG     = O_QR + 1048576;       // 8*16*512*64 bf  2,097,152
static const size_t O_VG     = O_KG + 2097152;       //                 2,097,152
static const size_t O_RHKT   = O_SCR + 8388608;      // 16*512*64 bf      262,144
static const size_t O_VECBF  = O_SCR + 8650752;      // 2048x1024 bf    1,048,576
static const size_t O_TATTN  = O_SCR + 9699328;      // 2048x1024 f32   2,097,152
static const size_t O_BDS    = O_SCR + 11796480;     // 128*256*512 bf  (span 8,388,608 floats)
static const size_t O_T1BF   = O_BDS;
static const size_t O_T2     = O_BDS + 4194304;
static const size_t O_T2B    = O_T2 + 2097152;
static const size_t O_PMAX   = O_SCR + 16384000;     // 2048*250          512,000
static const size_t O_PSUM   = O_PMAX + 512000;      //                   512,000
static const size_t O_LSE    = O_PSUM + 512000;      // 2048
static const size_t O_TGT    = O_LSE + 2048;         // 2048

// ---------------- fused prep kernel (R17/R19/R20 compaction) ----------------
// Blocks 0..26623: 10 weight transposes (2 layers x 5 weights).
// Blocks 26624..33279: embed (2048) + posemb (512) + mems->bf16 (4096).
__global__ __launch_bounds__(256) void prep_all_kernel(
    const float* __restrict__ qkv_w, const float* __restrict__ r_w,
    const float* __restrict__ o_w, const float* __restrict__ ff_w1,
    const float* __restrict__ ff_w2,
    ushort* __restrict__ qkvt, ushort* __restrict__ rwt, ushort* __restrict__ owt,
    ushort* __restrict__ ffw1t, ushort* __restrict__ ffw2t,
    const int* __restrict__ dec, const float* __restrict__ emb,
    float* __restrict__ h, ushort* __restrict__ hb,
    ushort* __restrict__ pe, const float* __restrict__ mems,
    ushort* __restrict__ membf) {
    __shared__ float tile[32][33];
    int id = blockIdx.x;
    if (id >= 26624) {
        id -= 26624;
        if (id < 2048) {
            int t = id;
            int tok = dec[t];
            const float* src = emb + (size_t)tok * DMODEL;
            float* dst = h + (size_t)t * DMODEL;
            ushort* dstb = hb + (size_t)t * DMODEL;
            for (int u = 0; u < 4; ++u) {
                int d = threadIdx.x + u * 256;
                float v = src[d] * 32.0f;
                dst[d] = v;
                dstb[d] = f2b(v);
            }
        } else if (id < 2560) {
            int r = id - 2048;
            float pos = (float)(KLEN - 1 - r);
            for (int u = 0; u < 2; ++u) {
                int dp = threadIdx.x + u * 256;
                float inv = expf(-(float)dp * (9.210340371976184f / 512.0f));
                float ang = pos * inv;
                pe[(size_t)r * DMODEL + dp]       = f2b(sinf(ang));
                pe[(size_t)r * DMODEL + 512 + dp] = f2b(cosf(ang));
            }
        } else {
            size_t i = (size_t)(id - 2560) * 256 + threadIdx.x;
            float4 v = ((const float4*)mems)[i];
            ushort4 o;
            o.x = f2b(v.x); o.y = f2b(v.y); o.z = f2b(v.z); o.w = f2b(v.w);
            ((ushort4*)membf)[i] = o;
        }
        return;
    }
    int l = (id >= 13312) ? 1 : 0;
    id -= l * 13312;
    const float* W; ushort* Wt; int K, N, nbx;
    if (id < 3072) {
        W = qkv_w + (size_t)l * DMODEL * 3072; Wt = qkvt + (size_t)l * 3072 * DMODEL;
        K = DMODEL; N = 3072; nbx = 96;
    } else if (id < 4096) {
        id -= 3072;
        W = r_w + (size_t)l * DMODEL * DMODEL; Wt = rwt + (size_t)l * DMODEL * DMODEL;
        K = DMODEL; N = DMODEL; nbx = 32;
    } else if (id < 5120) {
        id -= 4096;
        W = o_w + (size_t)l * DMODEL * DMODEL; Wt = owt + (size_t)l * DMODEL * DMODEL;
        K = DMODEL; N = DMODEL; nbx = 32;
    } else if (id < 9216) {
        id -= 5120;
        W = ff_w1 + (size_t)l * DMODEL * DINNER; Wt = ffw1t + (size_t)l * DINNER * DMODEL;
        K = DMODEL; N = DINNER; nbx = 128;
    } else {
        id -= 9216;
        W = ff_w2 + (size_t)l * DINNER * DMODEL; Wt = ffw2t + (size_t)l * DMODEL * DINNER;
        K = DINNER; N = DMODEL; nbx = 32;
    }
    int bx = id % nbx, by = id / nbx;
    int n0 = bx * 32, k0 = by * 32;
    int tx = threadIdx.x & 31, ty = threadIdx.x >> 5;
    for (int u = 0; u < 4; ++u)
        tile[ty + u * 8][tx] = W[(size_t)(k0 + ty + u * 8) * N + n0 + tx];
    __syncthreads();
    for (int u = 0; u < 4; ++u)
        Wt[(size_t)(n0 + ty + u * 8) * K + k0 + tx] = f2b(tile[tx][ty + u * 8]);
}

// XCD-aware bijective swizzle for nwg % 8 == 0 (contiguous logical chunk per XCD)
__device__ __forceinline__ int xcd_swizzle(int bid, int nwg) {
    int cpx = nwg >> 3;
    return (bid & 7) * cpx + (bid >> 3);
}

// ------- GEMM body, DMA-staged, 2-phase double-buffer, general strides.
#define GEMM_BODY_DMA_DB2(APTR, BPTR, KEXT, LDA, LDB)                          \
    const int tid = threadIdx.x;                                               \
    const int wave = tid >> 6, lane = tid & 63;                                \
    const int wr = wave >> 1, wc = wave & 1;                                   \
    const int fr = lane & 15, kq = lane >> 4;                                  \
    const int srow = wave * 16 + (lane >> 2);                                  \
    const int scol = 8 * ((lane & 3) ^ ((lane >> 3) & 3));                     \
    const int rsw  = 8 * (kq ^ ((fr >> 1) & 3));                               \
    const ushort* Ap = (APTR) + (size_t)(m0 + srow) * (LDA) + scol;            \
    const ushort* Bp = (BPTR) + (size_t)(n0 + srow) * (LDB) + scol;            \
    ushort* Al = &As[wave * 512];                                              \
    ushort* Bl = &Bs[wave * 512];                                              \
    const ushort* Ard = &As[(wr * 64 + fr) * 32 + rsw];                        \
    const ushort* Brd = &Bs[(wc * 64 + fr) * 32 + rsw];                        \
    const size_t halfA = (size_t)64 * (LDA);                                   \
    const size_t halfB = (size_t)64 * (LDB);                                   \
    const int nk = (KEXT) / 32;                                                \
    gload16(Ap, Al);                                                           \
    gload16(Ap + halfA, Al + 2048);                                            \
    gload16(Bp, Bl);                                                           \
    gload16(Bp + halfB, Bl + 2048);                                            \
    f32x4 acc[4][4] = {};                                                      \
    int cur = 0;                                                               \
    for (int t = 0; t < nk; ++t) {                                             \
        __syncthreads();                                                       \
        if (t + 1 < nk) {                                                      \
            const int kn = (t + 1) * 32;                                       \
            const int nxt = (cur ^ 1) * 4096;                                  \
            gload16(Ap + kn, Al + nxt);                                        \
            gload16(Ap + kn + halfA, Al + nxt + 2048);                         \
            gload16(Bp + kn, Bl + nxt);                                        \
            gload16(Bp + kn + halfB, Bl + nxt + 2048);                         \
        }                                                                      \
        const ushort* Ardc = Ard + cur * 4096;                                 \
        const ushort* Brdc = Brd + cur * 4096;                                 \
        bf16x8 af[4], bfr[4];                                                  \
        _Pragma("unroll")                                                      \
        for (int i = 0; i < 4; ++i) af[i]  = *(const bf16x8*)(Ardc + i * 16 * 32); \
        _Pragma("unroll")                                                      \
        for (int i = 0; i < 4; ++i) bfr[i] = *(const bf16x8*)(Brdc + i * 16 * 32); \
        _Pragma("unroll")                                                      \
        for (int mi = 0; mi < 4; ++mi)                                         \
            _Pragma("unroll")                                                  \
            for (int ni = 0; ni < 4; ++ni)                                     \
                acc[mi][ni] = __builtin_amdgcn_mfma_f32_16x16x32_bf16(         \
                    af[mi], bfr[ni], acc[mi][ni], 0, 0, 0);                    \
        cur ^= 1;                                                              \
    }

#define GEMM_BODY_DMA_DB(APTR, BPTR, KDIM) GEMM_BODY_DMA_DB2(APTR, BPTR, KDIM, KDIM, KDIM)

// ------- GEMM body, register-staged (R3-proven, pitch LPAD=40) -------
#define GEMM_BODY_REG(APTR, BPTR, KDIM)                                        \
    const int tid = threadIdx.x;                                               \
    const int wave = tid >> 6, lane = tid & 63;                                \
    const int wr = wave >> 1, wc = wave & 1;                                   \
    const int srow = tid >> 1, shalf = tid & 1;                                \
    const ushort* Ap = (APTR) + (size_t)(m0 + srow) * (KDIM) + shalf * 16;     \
    const ushort* Bp = (BPTR) + (size_t)(n0 + srow) * (KDIM) + shalf * 16;     \
    ushort* Asw = &As[srow * LPAD + shalf * 16];                               \
    ushort* Bsw = &Bs[srow * LPAD + shalf * 16];                               \
    const int fr = lane & 15, kq = lane >> 4;                                  \
    const ushort* Ard = &As[(wr * 64 + fr) * LPAD + kq * 8];                   \
    const ushort* Brd = &Bs[(wc * 64 + fr) * LPAD + kq * 8];                   \
    f32x4 acc[4][4] = {};                                                      \
    for (int k0 = 0; k0 < (KDIM); k0 += 32) {                                  \
        float4 a0 = *(const float4*)(Ap + k0);                                 \
        float4 a1 = *(const float4*)(Ap + k0 + 8);                             \
        float4 b0 = *(const float4*)(Bp + k0);                                 \
        float4 b1 = *(const float4*)(Bp + k0 + 8);                             \
        *(float4*)(Asw)     = a0; *(float4*)(Asw + 8) = a1;                    \
        *(float4*)(Bsw)     = b0; *(float4*)(Bsw + 8) = b1;                    \
        __syncthreads();                                                       \
        bf16x8 af[4], bfr[4];                                                  \
        _Pragma("unroll")                                                      \
        for (int i = 0; i < 4; ++i) af[i]  = *(const bf16x8*)(Ard + i * 16 * LPAD); \
        _Pragma("unroll")                                                      \
        for (int i = 0; i < 4; ++i) bfr[i] = *(const bf16x8*)(Brd + i * 16 * LPAD); \
        _Pragma("unroll")                                                      \
        for (int mi = 0; mi < 4; ++mi)                                         \
            _Pragma("unroll")                                                  \
            for (int ni = 0; ni < 4; ++ni)                                     \
                acc[mi][ni] = __builtin_amdgcn_mfma_f32_16x16x32_bf16(         \
                    af[mi], bfr[ni], acc[mi][ni], 0, 0, 0);                    \
        __syncthreads();                                                       \
    }

// generic: C = A * Bt^T (+bias)(+relu), bf16 or f32 out. grid dim3(N/128, M/128)
template<int OUTBF, int ACT>
__global__ __launch_bounds__(256) void gemm_bf16_kernel(
    const ushort* __restrict__ A, const ushort* __restrict__ Bt,
    const float* __restrict__ bias, void* __restrict__ Cout,
    int M, int N, int K) {
    __shared__ ushort As[2 * 128 * 32];
    __shared__ ushort Bs[2 * 128 * 32];
    int m0 = blockIdx.y * 128, n0 = blockIdx.x * 128;
    GEMM_BODY_DMA_DB(A, Bt, K)
    float* Cf  = (float*)Cout;
    ushort* Cb = (ushort*)Cout;
    #pragma unroll
    for (int ni = 0; ni < 4; ++ni) {
        int cg = n0 + wc * 64 + ni * 16 + fr;
        float bv = bias ? bias[cg] : 0.0f;
        #pragma unroll
        for (int mi = 0; mi < 4; ++mi) {
            int rg = m0 + wr * 64 + mi * 16 + kq * 4;
            #pragma unroll
            for (int r = 0; r < 4; ++r) {
                float v = acc[mi][ni][r] + bv;
                if (ACT) v = fmaxf(v, 0.0f);
                if (OUTBF) Cb[(size_t)(rg + r) * N + cg] = f2b(v);
                else       Cf[(size_t)(rg + r) * N + cg] = v;
            }
        }
    }
}

// split-K=4 GEMM (ow/ff2): grid dim3(N/128, M/128, 4).
__global__ __launch_bounds__(256) void gemm_splitk4_kernel(
    const ushort* __restrict__ A, const ushort* __restrict__ Bt,
    const float* __restrict__ bias,
    float* __restrict__ C0, float* __restrict__ C1,
    float* __restrict__ C2, float* __restrict__ C3,
    int N, int K) {
    __shared__ ushort As[2 * 128 * 32];
    __shared__ ushort Bs[2 * 128 * 32];
    int m0 = blockIdx.y * 128, n0 = blockIdx.x * 128;
    const int z = blockIdx.z;
    const int kext = K >> 2;
    const ushort* Az = A + (size_t)z * kext;
    const ushort* Bz = Bt + (size_t)z * kext;
    GEMM_BODY_DMA_DB2(Az, Bz, kext, K, K)
    float* Cf = (z == 0) ? C0 : (z == 1) ? C1 : (z == 2) ? C2 : C3;
    const float* bp = (z == 0) ? bias : nullptr;
    #pragma unroll
    for (int ni = 0; ni < 4; ++ni) {
        int cg = n0 + wc * 64 + ni * 16 + fr;
        float bv = bp ? bp[cg] : 0.0f;
        #pragma unroll
        for (int mi = 0; mi < 4; ++mi) {
            int rg = m0 + wr * 64 + mi * 16 + kq * 4;
            #pragma unroll
            for (int r = 0; r < 4; ++r)
                Cf[(size_t)(rg + r) * N + cg] = acc[mi][ni][r] + bv;
        }
    }
}

// QKV (blocks 0..767) + rhk (blocks 768..799) fused (R17 compaction).
__global__ __launch_bounds__(256) void qkv_rhk_kernel(
    const ushort* __restrict__ Am, const ushort* __restrict__ Ah,
    const ushort* __restrict__ Bt,
    const float* __restrict__ rwb, const float* __restrict__ rrb,
    ushort* __restrict__ Qw, ushort* __restrict__ Qr,
    ushort* __restrict__ Kg, ushort* __restrict__ Vg,
    const ushort* __restrict__ Apos, const ushort* __restrict__ Brw,
    ushort* __restrict__ rhkT) {
    __shared__ ushort As[2 * 128 * 32];
    __shared__ ushort Bs[2 * 128 * 32];
    if (blockIdx.x < 768) {
        int id = blockIdx.x;
        int m0 = (id / 24) * 128, n0 = (id % 24) * 128;
        const ushort* Aeff = (m0 < 2048) ? Am : (Ah - (size_t)2048 * DMODEL);
        GEMM_BODY_DMA_DB(Aeff, Bt, DMODEL)
        #pragma unroll
        for (int ni = 0; ni < 4; ++ni) {
            int e = n0 + wc * 64 + ni * 16 + fr;
            #pragma unroll
            for (int mi = 0; mi < 4; ++mi) {
                int rg = m0 + wr * 64 + mi * 16 + kq * 4;
                #pragma unroll
                for (int r = 0; r < 4; ++r) {
                    float v = acc[mi][ni][r];
                    int m = rg + r;
                    int b_ = m & 7, jr = m >> 3;
                    if (e < 1024) {
                        if (m >= 2048) {
                            int n_ = e >> 6, d_ = e & 63, i_ = jr - 256;
                            size_t qa = (((size_t)b_ * 16 + n_) * 256 + i_) * 64 + d_;
                            Qw[qa] = f2b(v + rwb[e]);
                            Qr[qa] = f2b(v + rrb[e]);
                        }
                    } else if (e < 2048) {
                        int e2 = e - 1024;
                        int n_ = e2 >> 6, d_ = e2 & 63;
                        Kg[(((size_t)b_ * 16 + n_) * 512 + jr) * 64 + d_] = f2b(v);
                    } else {
                        int e2 = e - 2048;
                        int n_ = e2 >> 6, d_ = e2 & 63;
                        Vg[(((size_t)b_ * 16 + n_) * 512 + jr) * 64 + d_] = f2b(v);
                    }
                }
            }
        }
    } else {
        int rid = blockIdx.x - 768;
        int m0 = (rid / 8) * 128, n0 = (rid % 8) * 128;
        GEMM_BODY_REG(Apos, Brw, DMODEL)
        #pragma unroll
        for (int ni = 0; ni < 4; ++ni) {
            int e = n0 + wc * 64 + ni * 16 + fr;
            int n_ = e >> 6, d_ = e & 63;
            #pragma unroll
            for (int mi = 0; mi < 4; ++mi) {
                int rg = m0 + wr * 64 + mi * 16 + kq * 4;
                #pragma unroll
                for (int r = 0; r < 4; ++r)
                    rhkT[((size_t)n_ * 512 + (rg + r)) * 64 + d_] = f2b(acc[mi][ni][r]);
            }
        }
    }
}

// BDfull per (b,n): Qr(256x64) @ rhkT_n(512x64)^T, rel-shift in epilogue.
__global__ __launch_bounds__(256) void bd_gemm_kernel(
    const ushort* __restrict__ QrAll, const ushort* __restrict__ rhkT,
    ushort* __restrict__ BDs) {
    __shared__ ushort As[2 * 128 * 32];
    __shared__ ushort Bs[2 * 128 * 32];
    int batch = blockIdx.z;                    // b*16+n
    const ushort* A  = QrAll + (size_t)batch * (256 * 64);
    const ushort* Bt = rhkT + (size_t)(batch & 15) * (512 * 64);
    ushort* BDb = BDs + (size_t)batch * (256 * 512);
    int m0 = blockIdx.y * 128, n0 = blockIdx.x * 128;
    GEMM_BODY_DMA_DB(A, Bt, 64)
    #pragma unroll
    for (int ni = 0; ni < 4; ++ni) {
        int rr = n0 + wc * 64 + ni * 16 + fr;
        #pragma unroll
        for (int mi = 0; mi < 4; ++mi) {
            int rg = m0 + wr * 64 + mi * 16 + kq * 4;
            #pragma unroll
            for (int r = 0; r < 4; ++r) {
                int i = rg + r;
                int j = rr + i - 255;
                if ((unsigned)j < 512u)
                    BDb[(size_t)i * 512 + j] = f2b(acc[mi][ni][r]);
            }
        }
    }
}

// ---------------- fused flash attention ----------------
__global__ __launch_bounds__(256) void fused_attn_kernel(
    const ushort* __restrict__ Qw, const ushort* __restrict__ Kg,
    const ushort* __restrict__ Vg, const ushort* __restrict__ BDs,
    ushort* __restrict__ vec) {
    __shared__ ushort Ks[64 * 72];
    __shared__ ushort Vt[64 * 72];
    __shared__ ushort Pl[4][16 * 72];
    const int qt = blockIdx.x, b = blockIdx.y, n = blockIdx.z;
    const int tid = threadIdx.x, wv = tid >> 6, lane = tid & 63;
    const int fr = lane & 15, kq = lane >> 4;
    const int q0 = qt * 64;
    const size_t bn = (size_t)b * 16 + n;
    const ushort* Qb  = Qw + bn * 256 * 64;
    const ushort* Kb  = Kg + bn * 512 * 64;
    const ushort* Vb  = Vg + bn * 512 * 64;
    const ushort* BDb = BDs + bn * 256 * 512;
    bf16x8 aq0, aq1;
    {
        const ushort* qp = Qb + (size_t)(q0 + wv * 16 + fr) * 64 + kq * 8;
        aq0 = *(const bf16x8*)qp;
        aq1 = *(const bf16x8*)(qp + 32);
    }
    f32x4 O[4] = {};
    float m_r[4], l_r[4];
    #pragma unroll
    for (int r = 0; r < 4; ++r) { m_r[r] = -INFINITY; l_r[r] = 0.0f; }
    const int NT = qt + 5;
    const int krow = tid >> 2, kseg = tid & 3;
    const int vrow = tid & 63, vseg0 = tid >> 6;
    for (int jt = 0; jt < NT; ++jt) {
        __syncthreads();
        {
            const ushort* src = Kb + (size_t)(jt * 64 + krow) * 64 + kseg * 16;
            *(float4*)&Ks[krow * 72 + kseg * 16]     = *(const float4*)src;
            *(float4*)&Ks[krow * 72 + kseg * 16 + 8] = *(const float4*)(src + 8);
        }
        #pragma unroll
        for (int it = 0; it < 2; ++it) {
            int seg = vseg0 + it * 4;
            const ushort* src = Vb + (size_t)(jt * 64 + vrow) * 64 + seg * 8;
            bf16x8 v = *(const bf16x8*)src;
            #pragma unroll
            for (int q = 0; q < 8; ++q)
                Vt[(seg * 8 + q) * 72 + vrow] = (ushort)v[q];
        }
        __syncthreads();
        f32x4 S[4] = {};
        #pragma unroll
        for (int cb = 0; cb < 4; ++cb) {
            const ushort* kp = &Ks[(cb * 16 + fr) * 72 + kq * 8];
            bf16x8 b0 = *(const bf16x8*)kp;
            bf16x8 b1 = *(const bf16x8*)(kp + 32);
            S[cb] = __builtin_amdgcn_mfma_f32_16x16x32_bf16(aq0, b0, S[cb], 0, 0, 0);
            S[cb] = __builtin_amdgcn_mfma_f32_16x16x32_bf16(aq1, b1, S[cb], 0, 0, 0);
        }
        #pragma unroll
        for (int cb = 0; cb < 4; ++cb) {
            int j = jt * 64 + cb * 16 + fr;
            #pragma unroll
            for (int r = 0; r < 4; ++r) {
                int i = q0 + wv * 16 + kq * 4 + r;
                float bd = b2f(BDb[(size_t)i * 512 + j]);
                float s = (S[cb][r] + bd) * 0.125f;
                S[cb][r] = (j <= i + 256) ? s : -1e30f;
            }
        }
        float sc[4];
        #pragma unroll
        for (int r = 0; r < 4; ++r) {
            float t = fmaxf(fmaxf(S[0][r], S[1][r]), fmaxf(S[2][r], S[3][r]));
            t = fmaxf(t, __shfl_xor(t, 1));
            t = fmaxf(t, __shfl_xor(t, 2));
            t = fmaxf(t, __shfl_xor(t, 4));
            t = fmaxf(t, __shfl_xor(t, 8));
            float mn = fmaxf(m_r[r], t);
            sc[r] = __expf(m_r[r] - mn);
            m_r[r] = mn;
        }
        float ts[4] = {0.0f, 0.0f, 0.0f, 0.0f};
        #pragma unroll
        for (int cb = 0; cb < 4; ++cb)
            #pragma unroll
            for (int r = 0; r < 4; ++r) {
                float p = __expf(S[cb][r] - m_r[r]);
                S[cb][r] = p;
                ts[r] += p;
            }
        #pragma unroll
        for (int r = 0; r < 4; ++r) {
            float t = ts[r];
            t += __shfl_xor(t, 1);
            t += __shfl_xor(t, 2);
            t += __shfl_xor(t, 4);
            t += __shfl_xor(t, 8);
            l_r[r] = l_r[r] * sc[r] + t;
            #pragma unroll
            for (int ob = 0; ob < 4; ++ob) O[ob][r] *= sc[r];
        }
        ushort* P = &Pl[wv][0];
        #pragma unroll
        for (int cb = 0; cb < 4; ++cb)
            #pragma unroll
            for (int r = 0; r < 4; ++r)
                P[(kq * 4 + r) * 72 + cb * 16 + fr] = f2b(S[cb][r]);
        asm volatile("s_waitcnt lgkmcnt(0)" ::: "memory");
        bf16x8 pa0 = *(const bf16x8*)&P[fr * 72 + kq * 8];
        bf16x8 pa1 = *(const bf16x8*)&P[fr * 72 + 32 + kq * 8];
        #pragma unroll
        for (int ob = 0; ob < 4; ++ob) {
            const ushort* vp = &Vt[(ob * 16 + fr) * 72 + kq * 8];
            bf16x8 v0 = *(const bf16x8*)vp;
            bf16x8 v1 = *(const bf16x8*)(vp + 32);
            O[ob] = __builtin_amdgcn_mfma_f32_16x16x32_bf16(pa0, v0, O[ob], 0, 0, 0);
            O[ob] = __builtin_amdgcn_mfma_f32_16x16x32_bf16(pa1, v1, O[ob], 0, 0, 0);
        }
    }
    #pragma unroll
    for (int r = 0; r < 4; ++r) {
        float inv = 1.0f / l_r[r];
        int i = q0 + wv * 16 + kq * 4 + r;
        size_t base = ((size_t)i * 8 + b) * 1024 + n * 64;
        #pragma unroll
        for (int ob = 0; ob < 4; ++ob)
            vec[base + ob * 16 + fr] = f2b(O[ob][r] * inv);
    }
}

// logits GEMM + fused per-token (max, sumexp) + fused tgt dot-products.
// R23: A-operand read DIRECTLY from f32 out_w (reg-staged f32->bf16 into the
// same linear LDS layout gload16 produced) -- eliminates the separate
// convert_bf16 dispatch (~31us of pure traffic). B stays gload16. Same
// barrier structure, same f2b rounding -> bit-identical results.
__global__ __launch_bounds__(256) void logits_lse_kernel(
    const float* __restrict__ Wf, const ushort* __restrict__ Bt,
    const float* __restrict__ ob, float* __restrict__ pmax, float* __restrict__ psum,
    const float* __restrict__ hf,
    const int* __restrict__ target, float* __restrict__ tgtout) {
    __shared__ ushort As[128 * 32];
    __shared__ ushort Bs[128 * 32];
    __shared__ float redm[2][128], reds[2][128];
    if (blockIdx.x >= 4000) {
        int wv2 = threadIdx.x >> 6, lane2 = threadIdx.x & 63;
        int t = (blockIdx.x - 4000) * 4 + wv2;
        int row = target[t];
        const float* hp = hf + (size_t)t * DMODEL;
        const float* wp = Wf + (size_t)row * DMODEL;
        float s = 0.0f;
        for (int d = lane2; d < DMODEL; d += 64) s += hp[d] * wp[d];
        for (int o = 32; o > 0; o >>= 1) s += __shfl_down(s, o);
        if (lane2 == 0) tgtout[t] = s + ob[row];
        return;
    }
    int logical = xcd_swizzle(blockIdx.x, 4000);
    int bx = logical / 16;       // vocab tile (slow)
    int by = logical % 16;       // token tile (fast)
    int m0 = bx * 128;           // vocab
    int n0 = by * 128;           // tokens
    const int tid = threadIdx.x;
    const int wave = tid >> 6, lane = tid & 63;
    const int wr = wave >> 1, wc = wave & 1;
    const int fr = lane & 15, kq = lane >> 4;
    const int srow = wave * 16 + (lane >> 2);
    const int scol = 8 * ((lane & 3) ^ ((lane >> 3) & 3));
    const int rsw  = 8 * (kq ^ ((fr >> 1) & 3));
    const float*  Af = Wf + (size_t)(m0 + srow) * DMODEL + scol;  // f32 A source
    const ushort* Bp = Bt + (size_t)(n0 + srow) * DMODEL + scol;
    ushort* Bl  = &Bs[wave * 512];
    // lane's 16B slot in the linear gload16-equivalent layout: 8 ushorts
    ushort* Asw = &As[wave * 512 + lane * 8];
    const ushort* Ard = &As[(wr * 64 + fr) * 32 + rsw];
    const ushort* Brd = &Bs[(wc * 64 + fr) * 32 + rsw];
    const size_t halfAf = (size_t)64 * DMODEL;   // +64 vocab rows (f32 elems)
    const size_t halfB  = (size_t)64 * DMODEL;   // +64 token rows (bf16 elems)
    f32x4 acc[4][4] = {};
    for (int k0 = 0; k0 < DMODEL; k0 += 32) {
        __syncthreads();
        gload16(Bp + k0, Bl);
        gload16(Bp + k0 + halfB, Bl + 2048);
        float4 a0 = *(const float4*)(Af + k0);
        float4 a1 = *(const float4*)(Af + k0 + 4);
        float4 a2 = *(const float4*)(Af + k0 + halfAf);
        float4 a3 = *(const float4*)(Af + k0 + halfAf + 4);
        *(bf16x8*)Asw          = pack8(a0, a1);
        *(bf16x8*)(Asw + 2048) = pack8(a2, a3);
        __syncthreads();
        bf16x8 af[4], bfr[4];
        #pragma unroll
        for (int i = 0; i < 4; ++i) af[i]  = *(const bf16x8*)(Ard + i * 16 * 32);
        #pragma unroll
        for (int i = 0; i < 4; ++i) bfr[i] = *(const bf16x8*)(Brd + i * 16 * 32);
        #pragma unroll
        for (int mi = 0; mi < 4; ++mi)
            #pragma unroll
            for (int ni = 0; ni < 4; ++ni)
                acc[mi][ni] = __builtin_amdgcn_mfma_f32_16x16x32_bf16(
                    af[mi], bfr[ni], acc[mi][ni], 0, 0, 0);
    }
    int t0 = n0;
    #pragma unroll
    for (int ni = 0; ni < 4; ++ni) {
        float vals[16];
        float vmax = -1e30f;
        #pragma unroll
        for (int mi = 0; mi < 4; ++mi) {
            int rg = m0 + wr * 64 + mi * 16 + kq * 4;
            float4 ob4 = *(const float4*)&ob[rg];
            float o4[4] = {ob4.x, ob4.y, ob4.z, ob4.w};
            #pragma unroll
            for (int r = 0; r < 4; ++r) {
                float v = acc[mi][ni][r] + o4[r];
                vals[mi * 4 + r] = v;
                vmax = fmaxf(vmax, v);
            }
        }
        vmax = fmaxf(vmax, __shfl_xor(vmax, 16));
        vmax = fmaxf(vmax, __shfl_xor(vmax, 32));
        float s = 0.0f;
        #pragma unroll
        for (int q = 0; q < 16; ++q) s += __expf(vals[q] - vmax);
        s += __shfl_xor(s, 16);
        s += __shfl_xor(s, 32);
        if (kq == 0) {
            redm[wr][wc * 64 + ni * 16 + fr] = vmax;
            reds[wr][wc * 64 + ni * 16 + fr] = s;
        }
    }
    __syncthreads();
    if (tid < 128) {
        float ma = redm[0][tid], mb = redm[1][tid];
        float m = fmaxf(ma, mb);
        float s = reds[0][tid] * __expf(ma - m) + reds[1][tid] * __expf(mb - m);
        pmax[(size_t)(t0 + tid) * VTILES + bx] = m;
        psum[(size_t)(t0 + tid) * VTILES + bx] = s;
    }
}

// h = LN(act(x0+x1+x2+x3) + h)*g + b, writes fp32 h and bf16 copy.
template<int RELU>
__global__ __launch_bounds__(256) void ln_combine4_kernel(const float* __restrict__ x0,
    const float* __restrict__ x1, const float* __restrict__ x2,
    const float* __restrict__ x3, float* __restrict__ h, const float* __restrict__ g,
    const float* __restrict__ bb, ushort* __restrict__ hb) {
    int t = blockIdx.x, tid = threadIdx.x;
    __shared__ float rs[256], rq[256];
    float v[4];
    float s = 0.0f, sq = 0.0f;
    for (int u = 0; u < 4; ++u) {
        int d = tid + u * 256;
        size_t idx = (size_t)t * DMODEL + d;
        float xx = (x0[idx] + x1[idx]) + (x2[idx] + x3[idx]);
        if (RELU) xx = fmaxf(xx, 0.0f);
        float val = xx + h[idx];
        v[u] = val; s += val; sq += val * val;
    }
    rs[tid] = s; rq[tid] = sq;
    __syncthreads();
    for (int st = 128; st > 0; st >>= 1) {
        if (tid < st) { rs[tid] += rs[tid + st]; rq[tid] += rq[tid + st]; }
        __syncthreads();
    }
    float mean = rs[0] * (1.0f / DMODEL);
    float var = rq[0] * (1.0f / DMODEL) - mean * mean;
    float r = rsqrtf(var + 1e-3f);
    for (int u = 0; u < 4; ++u) {
        int d = tid + u * 256;
        float o = (v[u] - mean) * r * g[d] + bb[d];
        h[(size_t)t * DMODEL + d] = o;
        hb[(size_t)t * DMODEL + d] = f2b(o);
    }
}

// ---------------- final loss pieces ----------------

// 512 blocks x 256 threads; wave wv handles token t = blk*4 + wv.
__global__ __launch_bounds__(256) void lse_kernel(const float* __restrict__ pmax,
    const float* __restrict__ psum, float* __restrict__ lse) {
    int wv = threadIdx.x >> 6, lane = threadIdx.x & 63;
    int t = blockIdx.x * 4 + wv;
    const float* pm = pmax + (size_t)t * VTILES;
    const float* ps = psum + (size_t)t * VTILES;
    float m = -1e30f;
    for (int c = lane; c < VTILES; c += 64) m = fmaxf(m, pm[c]);
    for (int o = 32; o > 0; o >>= 1) m = fmaxf(m, __shfl_xor(m, o));
    float s = 0.0f;
    for (int c = lane; c < VTILES; c += 64) s += ps[c] * expf(pm[c] - m);
    for (int o = 32; o > 0; o >>= 1) s += __shfl_xor(s, o);
    if (lane == 0) lse[t] = m + logf(s);
}

__global__ __launch_bounds__(256) void loss_kernel(const float* __restrict__ lse,
    const float* __restrict__ tgt, const float* __restrict__ vm, float* __restrict__ out) {
    __shared__ float red[256];
    int tid = threadIdx.x;
    float s = 0.0f;
    for (int t = tid; t < NTOK; t += 256) s += (lse[t] - tgt[t]) * vm[t];
    red[tid] = s;
    __syncthreads();
    for (int st = 128; st > 0; st >>= 1) {
        if (tid < st) red[tid] += red[tid + st];
        __syncthreads();
    }
    if (tid == 0) out[0] = red[0] * (1.0f / NTOK);
}

// ---------------- launch ----------------
extern "C" void kernel_launch(void* const* d_in, const int* in_sizes, int n_in,
                              void* d_out, int out_size, void* d_ws, size_t ws_size,
                              hipStream_t stream) {
    const int*   dec_inp   = (const int*)  d_in[0];
    const int*   target    = (const int*)  d_in[1];
    const float* valid     = (const float*)d_in[2];
    const float* mems      = (const float*)d_in[3];
    const float* vocab_emb = (const float*)d_in[4];
    const float* out_w     = (const float*)d_in[5];
    const float* out_b     = (const float*)d_in[6];
    const float* qkv_w     = (const float*)d_in[7];
    const float* r_w       = (const float*)d_in[8];
    const float* o_w       = (const float*)d_in[9];
    const float* ln1_g     = (const float*)d_in[10];
    const float* ln1_b     = (const float*)d_in[11];
    const float* ff_w1     = (const float*)d_in[12];
    const float* ff_b1     = (const float*)d_in[13];
    const float* ff_w2     = (const float*)d_in[14];
    const float* ff_b2     = (const float*)d_in[15];
    const float* ln2_g     = (const float*)d_in[16];
    const float* ln2_b     = (const float*)d_in[17];
    const float* r_w_bias  = (const float*)d_in[18];
    const float* r_r_bias  = (const float*)d_in[19];

    float* ws = (float*)d_ws;
    float*  h      = ws + O_H;
    ushort* hbf    = (ushort*)(ws + O_HBF);
    ushort* posbf  = (ushort*)(ws + O_POSBF);
    ushort* qkvt   = (ushort*)(ws + O_QKVT);
    ushort* rwt    = (ushort*)(ws + O_RWT);
    ushort* owt    = (ushort*)(ws + O_OWT);
    ushort* ffw1t  = (ushort*)(ws + O_FFW1T);
    ushort* ffw2t  = (ushort*)(ws + O_FFW2T);
    ushort* membf  = (ushort*)(ws + O_MEMBF);
    ushort* qwv    = (ushort*)(ws + O_QW);
    ushort* qrv    = (ushort*)(ws + O_QR);
    ushort* kg     = (ushort*)(ws + O_KG);
    ushort* vg     = (ushort*)(ws + O_VG);
    ushort* rhkT   = (ushort*)(ws + O_RHKT);
    ushort* vecbf  = (ushort*)(ws + O_VECBF);
    float*  tattn  = ws + O_TATTN;
    ushort* bds    = (ushort*)(ws + O_BDS);
    float*  owp0   = ws + O_BDS;
    float*  owp1   = ws + O_BDS + 2097152;
    float*  owp2   = ws + O_BDS + 4194304;
    float*  owp3   = ws + O_BDS + 6291456;
    ushort* t1bf   = (ushort*)(ws + O_T1BF);
    float*  t2     = ws + O_T2;
    float*  t2b    = ws + O_T2B;
    float*  ffp2   = tattn;
    float*  ffp3   = (float*)(ws + O_KG);
    float*  pmax   = ws + O_PMAX;
    float*  psum   = ws + O_PSUM;
    float*  lse    = ws + O_LSE;
    float*  tgt    = ws + O_TGT;

    prep_all_kernel<<<33280, 256, 0, stream>>>(
        qkv_w, r_w, o_w, ff_w1, ff_w2, qkvt, rwt, owt, ffw1t, ffw2t,
        dec_inp, vocab_emb, h, hbf, posbf, mems, membf);

    for (int l = 0; l < NLAYER; ++l) {
        qkv_rhk_kernel<<<800, 256, 0, stream>>>(
            membf + (size_t)l * 2097152, hbf,
            qkvt + (size_t)l * 3072 * DMODEL, r_w_bias, r_r_bias, qwv, qrv, kg, vg,
            posbf, rwt + (size_t)l * DMODEL * DMODEL, rhkT);
        bd_gemm_kernel<<<dim3(4, 2, 128), 256, 0, stream>>>(qrv, rhkT, bds);
        fused_attn_kernel<<<dim3(4, BSZ, NHEAD), 256, 0, stream>>>(qwv, kg, vg, bds, vecbf);
        gemm_splitk4_kernel<<<dim3(8, 16, 4), 256, 0, stream>>>(
            vecbf, owt + (size_t)l * DMODEL * DMODEL, nullptr,
            owp0, owp1, owp2, owp3, DMODEL, DMODEL);
        ln_combine4_kernel<0><<<NTOK, 256, 0, stream>>>(
            owp0, owp1, owp2, owp3, h, ln1_g + l * DMODEL, ln1_b + l * DMODEL, hbf);
        gemm_bf16_kernel<1, 1><<<dim3(32, 16), 256, 0, stream>>>(
            hbf, ffw1t + (size_t)l * DINNER * DMODEL, ff_b1 + (size_t)l * DINNER, t1bf, NTOK, DINNER, DMODEL);
        gemm_splitk4_kernel<<<dim3(8, 16, 4), 256, 0, stream>>>(
            t1bf, ffw2t + (size_t)l * DMODEL * DINNER, ff_b2 + (size_t)l * DMODEL,
            t2, t2b, ffp2, ffp3, DMODEL, DINNER);
        ln_combine4_kernel<1><<<NTOK, 256, 0, stream>>>(
            t2, t2b, ffp2, ffp3, h, ln2_g + l * DMODEL, ln2_b + l * DMODEL, hbf);
    }

    // logits reads out_w f32 directly (A reg-staged f32->bf16); no convert dispatch
    logits_lse_kernel<<<4512, 256, 0, stream>>>(
        out_w, hbf, out_b, pmax, psum, h, target, tgt);
    lse_kernel<<<512, 256, 0, stream>>>(pmax, psum, lse);
    loss_kernel<<<1, 256, 0, stream>>>(lse, tgt, valid, (float*)d_out);
}

// Round 24
// 655.231 us; speedup vs baseline: 1.1060x; 1.1060x over previous
//
#include <hip/hip_runtime.h>
#include <hip/hip_bf16.h>
#include <math.h>

// ---------------- problem constants ----------------
#define QLEN 256
#define MLEN 256
#define KLEN 512
#define BSZ 8
#define DMODEL 1024
#define NHEAD 16
#define DHEAD 64
#define DINNER 4096
#define NTOKEN 32000
#define NLAYER 2
#define NTOK 2048          // QLEN*BSZ
#define VTILES 250         // 32000/128
#define LPAD 40            // reg-staged LDS row pitch (R3-proven)

typedef __attribute__((ext_vector_type(8))) short bf16x8;
typedef __attribute__((ext_vector_type(4))) float f32x4;

__device__ __forceinline__ float b2f(ushort u) { return __uint_as_float(((unsigned)u) << 16); }
__device__ __forceinline__ ushort f2b(float x) {
  unsigned u = __float_as_uint(x);
  return (ushort)((u + 0x7fffu + ((u >> 16) & 1u)) >> 16);
}

// async global->LDS, 16B per lane. lds ptr must be wave-uniform base; HW adds lane*16.
__device__ __forceinline__ void gload16(const ushort* g, ushort* l) {
    __builtin_amdgcn_global_load_lds(
        (const __attribute__((address_space(1))) unsigned int*)(g),
        (__attribute__((address_space(3))) unsigned int*)(l), 16, 0, 0);
}

// ---------------- workspace layout (float offsets) ----------------
static const size_t O_H      = 0;                    // h fp32          2,097,152
static const size_t O_HBF    = 2097152;              // h bf16          1,048,576
static const size_t O_POSBF  = 3145728;              // pos bf16          262,144
static const size_t O_QKVT   = 3407872;              // 2x 3072x1024 bf 3,145,728
static const size_t O_RWT    = O_QKVT + 3145728;     // 2x 1024x1024 bf 1,048,576
static const size_t O_OWT    = O_RWT + 1048576;      // 2x 1024x1024 bf 1,048,576
static const size_t O_FFW1T  = O_OWT + 1048576;      // 2x 4096x1024 bf 4,194,304
static const size_t O_FFW2T  = O_FFW1T + 4194304;    // 2x 1024x4096 bf 4,194,304
static const size_t O_SCR    = O_FFW2T + 4194304;    // = 17,039,360
static const size_t O_MEMBF  = O_SCR;                // 2x 2048x1024 bf 2,097,152
static const size_t O_QW     = O_SCR + 2097152;      // 8*16*256*64 bf  1,048,576
static const size_t O_QR     = O_QW + 1048576;       //                 1,048,576
static const size_t O_KG     = O_QR + 1048576;       // 8*16*512*64 bf  2,097,152
static const size_t O_VG     = O_KG + 2097152;       //                 2,097,152
static const size_t O_RHKT   = O_SCR + 8388608;      // 16*512*64 bf      262,144
static const size_t O_VECBF  = O_SCR + 8650752;      // 2048x1024 bf    1,048,576
static const size_t O_TATTN  = O_SCR + 9699328;      // 2048x1024 f32   2,097,152
static const size_t O_BDS    = O_SCR + 11796480;     // 128*256*512 bf  (span 8,388,608 floats)
static const size_t O_T1BF   = O_BDS;
static const size_t O_T2     = O_BDS + 4194304;
static const size_t O_T2B    = O_T2 + 2097152;
static const size_t O_OUTWBF = O_SCR;                // 32000x1024 bf  16,384,000 (logits phase)
static const size_t O_PMAX   = O_SCR + 16384000;     // 2048*250          512,000
static const size_t O_PSUM   = O_PMAX + 512000;      //                   512,000
static const size_t O_LSE    = O_PSUM + 512000;      // 2048
static const size_t O_TGT    = O_LSE + 2048;         // 2048

// ---------------- fused prep kernel (R17/R19/R20 compaction) ----------------
// Blocks 0..26623: 10 weight transposes (2 layers x 5 weights).
// Blocks 26624..33279: embed (2048) + posemb (512) + mems->bf16 (4096).
__global__ __launch_bounds__(256) void prep_all_kernel(
    const float* __restrict__ qkv_w, const float* __restrict__ r_w,
    const float* __restrict__ o_w, const float* __restrict__ ff_w1,
    const float* __restrict__ ff_w2,
    ushort* __restrict__ qkvt, ushort* __restrict__ rwt, ushort* __restrict__ owt,
    ushort* __restrict__ ffw1t, ushort* __restrict__ ffw2t,
    const int* __restrict__ dec, const float* __restrict__ emb,
    float* __restrict__ h, ushort* __restrict__ hb,
    ushort* __restrict__ pe, const float* __restrict__ mems,
    ushort* __restrict__ membf) {
    __shared__ float tile[32][33];
    int id = blockIdx.x;
    if (id >= 26624) {
        id -= 26624;
        if (id < 2048) {
            int t = id;
            int tok = dec[t];
            const float* src = emb + (size_t)tok * DMODEL;
            float* dst = h + (size_t)t * DMODEL;
            ushort* dstb = hb + (size_t)t * DMODEL;
            for (int u = 0; u < 4; ++u) {
                int d = threadIdx.x + u * 256;
                float v = src[d] * 32.0f;
                dst[d] = v;
                dstb[d] = f2b(v);
            }
        } else if (id < 2560) {
            int r = id - 2048;
            float pos = (float)(KLEN - 1 - r);
            for (int u = 0; u < 2; ++u) {
                int dp = threadIdx.x + u * 256;
                float inv = expf(-(float)dp * (9.210340371976184f / 512.0f));
                float ang = pos * inv;
                pe[(size_t)r * DMODEL + dp]       = f2b(sinf(ang));
                pe[(size_t)r * DMODEL + 512 + dp] = f2b(cosf(ang));
            }
        } else {
            size_t i = (size_t)(id - 2560) * 256 + threadIdx.x;
            float4 v = ((const float4*)mems)[i];
            ushort4 o;
            o.x = f2b(v.x); o.y = f2b(v.y); o.z = f2b(v.z); o.w = f2b(v.w);
            ((ushort4*)membf)[i] = o;
        }
        return;
    }
    int l = (id >= 13312) ? 1 : 0;
    id -= l * 13312;
    const float* W; ushort* Wt; int K, N, nbx;
    if (id < 3072) {
        W = qkv_w + (size_t)l * DMODEL * 3072; Wt = qkvt + (size_t)l * 3072 * DMODEL;
        K = DMODEL; N = 3072; nbx = 96;
    } else if (id < 4096) {
        id -= 3072;
        W = r_w + (size_t)l * DMODEL * DMODEL; Wt = rwt + (size_t)l * DMODEL * DMODEL;
        K = DMODEL; N = DMODEL; nbx = 32;
    } else if (id < 5120) {
        id -= 4096;
        W = o_w + (size_t)l * DMODEL * DMODEL; Wt = owt + (size_t)l * DMODEL * DMODEL;
        K = DMODEL; N = DMODEL; nbx = 32;
    } else if (id < 9216) {
        id -= 5120;
        W = ff_w1 + (size_t)l * DMODEL * DINNER; Wt = ffw1t + (size_t)l * DINNER * DMODEL;
        K = DMODEL; N = DINNER; nbx = 128;
    } else {
        id -= 9216;
        W = ff_w2 + (size_t)l * DINNER * DMODEL; Wt = ffw2t + (size_t)l * DMODEL * DINNER;
        K = DINNER; N = DMODEL; nbx = 32;
    }
    int bx = id % nbx, by = id / nbx;
    int n0 = bx * 32, k0 = by * 32;
    int tx = threadIdx.x & 31, ty = threadIdx.x >> 5;
    for (int u = 0; u < 4; ++u)
        tile[ty + u * 8][tx] = W[(size_t)(k0 + ty + u * 8) * N + n0 + tx];
    __syncthreads();
    for (int u = 0; u < 4; ++u)
        Wt[(size_t)(n0 + ty + u * 8) * K + k0 + tx] = f2b(tile[tx][ty + u * 8]);
}

__global__ __launch_bounds__(256) void convert_bf16_kernel(const float* __restrict__ W,
    ushort* __restrict__ Wb) {
    size_t i = (size_t)blockIdx.x * 256 + threadIdx.x;
    float4 v = ((const float4*)W)[i];
    ushort4 o;
    o.x = f2b(v.x); o.y = f2b(v.y); o.z = f2b(v.z); o.w = f2b(v.w);
    ((ushort4*)Wb)[i] = o;
}

// XCD-aware bijective swizzle for nwg % 8 == 0 (contiguous logical chunk per XCD)
__device__ __forceinline__ int xcd_swizzle(int bid, int nwg) {
    int cpx = nwg >> 3;
    return (bid & 7) * cpx + (bid >> 3);
}

// ------- GEMM body, DMA-staged, 2-phase double-buffer, general strides.
#define GEMM_BODY_DMA_DB2(APTR, BPTR, KEXT, LDA, LDB)                          \
    const int tid = threadIdx.x;                                               \
    const int wave = tid >> 6, lane = tid & 63;                                \
    const int wr = wave >> 1, wc = wave & 1;                                   \
    const int fr = lane & 15, kq = lane >> 4;                                  \
    const int srow = wave * 16 + (lane >> 2);                                  \
    const int scol = 8 * ((lane & 3) ^ ((lane >> 3) & 3));                     \
    const int rsw  = 8 * (kq ^ ((fr >> 1) & 3));                               \
    const ushort* Ap = (APTR) + (size_t)(m0 + srow) * (LDA) + scol;            \
    const ushort* Bp = (BPTR) + (size_t)(n0 + srow) * (LDB) + scol;            \
    ushort* Al = &As[wave * 512];                                              \
    ushort* Bl = &Bs[wave * 512];                                              \
    const ushort* Ard = &As[(wr * 64 + fr) * 32 + rsw];                        \
    const ushort* Brd = &Bs[(wc * 64 + fr) * 32 + rsw];                        \
    const size_t halfA = (size_t)64 * (LDA);                                   \
    const size_t halfB = (size_t)64 * (LDB);                                   \
    const int nk = (KEXT) / 32;                                                \
    gload16(Ap, Al);                                                           \
    gload16(Ap + halfA, Al + 2048);                                            \
    gload16(Bp, Bl);                                                           \
    gload16(Bp + halfB, Bl + 2048);                                            \
    f32x4 acc[4][4] = {};                                                      \
    int cur = 0;                                                               \
    for (int t = 0; t < nk; ++t) {                                             \
        __syncthreads();                                                       \
        if (t + 1 < nk) {                                                      \
            const int kn = (t + 1) * 32;                                       \
            const int nxt = (cur ^ 1) * 4096;                                  \
            gload16(Ap + kn, Al + nxt);                                        \
            gload16(Ap + kn + halfA, Al + nxt + 2048);                         \
            gload16(Bp + kn, Bl + nxt);                                        \
            gload16(Bp + kn + halfB, Bl + nxt + 2048);                         \
        }                                                                      \
        const ushort* Ardc = Ard + cur * 4096;                                 \
        const ushort* Brdc = Brd + cur * 4096;                                 \
        bf16x8 af[4], bfr[4];                                                  \
        _Pragma("unroll")                                                      \
        for (int i = 0; i < 4; ++i) af[i]  = *(const bf16x8*)(Ardc + i * 16 * 32); \
        _Pragma("unroll")                                                      \
        for (int i = 0; i < 4; ++i) bfr[i] = *(const bf16x8*)(Brdc + i * 16 * 32); \
        _Pragma("unroll")                                                      \
        for (int mi = 0; mi < 4; ++mi)                                         \
            _Pragma("unroll")                                                  \
            for (int ni = 0; ni < 4; ++ni)                                     \
                acc[mi][ni] = __builtin_amdgcn_mfma_f32_16x16x32_bf16(         \
                    af[mi], bfr[ni], acc[mi][ni], 0, 0, 0);                    \
        cur ^= 1;                                                              \
    }

#define GEMM_BODY_DMA_DB(APTR, BPTR, KDIM) GEMM_BODY_DMA_DB2(APTR, BPTR, KDIM, KDIM, KDIM)

// ------- GEMM body, DMA-staged single-buffer BK=32 (logits best) --
#define GEMM_BODY_DMA_SB(APTR, BPTR, KDIM)                                     \
    const int tid = threadIdx.x;                                               \
    const int wave = tid >> 6, lane = tid & 63;                                \
    const int wr = wave >> 1, wc = wave & 1;                                   \
    const int fr = lane & 15, kq = lane >> 4;                                  \
    const int srow = wave * 16 + (lane >> 2);                                  \
    const int scol = 8 * ((lane & 3) ^ ((lane >> 3) & 3));                     \
    const int rsw  = 8 * (kq ^ ((fr >> 1) & 3));                               \
    const ushort* Ap = (APTR) + (size_t)(m0 + srow) * (KDIM) + scol;           \
    const ushort* Bp = (BPTR) + (size_t)(n0 + srow) * (KDIM) + scol;           \
    ushort* Al = &As[wave * 512];                                              \
    ushort* Bl = &Bs[wave * 512];                                              \
    const ushort* Ard = &As[(wr * 64 + fr) * 32 + rsw];                        \
    const ushort* Brd = &Bs[(wc * 64 + fr) * 32 + rsw];                        \
    const size_t halfstep = (size_t)64 * (KDIM);                               \
    f32x4 acc[4][4] = {};                                                      \
    for (int k0 = 0; k0 < (KDIM); k0 += 32) {                                  \
        __syncthreads();                                                       \
        gload16(Ap + k0, Al);                                                  \
        gload16(Ap + k0 + halfstep, Al + 2048);                                \
        gload16(Bp + k0, Bl);                                                  \
        gload16(Bp + k0 + halfstep, Bl + 2048);                                \
        __syncthreads();                                                       \
        bf16x8 af[4], bfr[4];                                                  \
        _Pragma("unroll")                                                      \
        for (int i = 0; i < 4; ++i) af[i]  = *(const bf16x8*)(Ard + i * 16 * 32); \
        _Pragma("unroll")                                                      \
        for (int i = 0; i < 4; ++i) bfr[i] = *(const bf16x8*)(Brd + i * 16 * 32); \
        _Pragma("unroll")                                                      \
        for (int mi = 0; mi < 4; ++mi)                                         \
            _Pragma("unroll")                                                  \
            for (int ni = 0; ni < 4; ++ni)                                     \
                acc[mi][ni] = __builtin_amdgcn_mfma_f32_16x16x32_bf16(         \
                    af[mi], bfr[ni], acc[mi][ni], 0, 0, 0);                    \
    }

// ------- GEMM body, register-staged (R3-proven, pitch LPAD=40) -------
#define GEMM_BODY_REG(APTR, BPTR, KDIM)                                        \
    const int tid = threadIdx.x;                                               \
    const int wave = tid >> 6, lane = tid & 63;                                \
    const int wr = wave >> 1, wc = wave & 1;                                   \
    const int srow = tid >> 1, shalf = tid & 1;                                \
    const ushort* Ap = (APTR) + (size_t)(m0 + srow) * (KDIM) + shalf * 16;     \
    const ushort* Bp = (BPTR) + (size_t)(n0 + srow) * (KDIM) + shalf * 16;     \
    ushort* Asw = &As[srow * LPAD + shalf * 16];                               \
    ushort* Bsw = &Bs[srow * LPAD + shalf * 16];                               \
    const int fr = lane & 15, kq = lane >> 4;                                  \
    const ushort* Ard = &As[(wr * 64 + fr) * LPAD + kq * 8];                   \
    const ushort* Brd = &Bs[(wc * 64 + fr) * LPAD + kq * 8];                   \
    f32x4 acc[4][4] = {};                                                      \
    for (int k0 = 0; k0 < (KDIM); k0 += 32) {                                  \
        float4 a0 = *(const float4*)(Ap + k0);                                 \
        float4 a1 = *(const float4*)(Ap + k0 + 8);                             \
        float4 b0 = *(const float4*)(Bp + k0);                                 \
        float4 b1 = *(const float4*)(Bp + k0 + 8);                             \
        *(float4*)(Asw)     = a0; *(float4*)(Asw + 8) = a1;                    \
        *(float4*)(Bsw)     = b0; *(float4*)(Bsw + 8) = b1;                    \
        __syncthreads();                                                       \
        bf16x8 af[4], bfr[4];                                                  \
        _Pragma("unroll")                                                      \
        for (int i = 0; i < 4; ++i) af[i]  = *(const bf16x8*)(Ard + i * 16 * LPAD); \
        _Pragma("unroll")                                                      \
        for (int i = 0; i < 4; ++i) bfr[i] = *(const bf16x8*)(Brd + i * 16 * LPAD); \
        _Pragma("unroll")                                                      \
        for (int mi = 0; mi < 4; ++mi)                                         \
            _Pragma("unroll")                                                  \
            for (int ni = 0; ni < 4; ++ni)                                     \
                acc[mi][ni] = __builtin_amdgcn_mfma_f32_16x16x32_bf16(         \
                    af[mi], bfr[ni], acc[mi][ni], 0, 0, 0);                    \
        __syncthreads();                                                       \
    }

// generic: C = A * Bt^T (+bias)(+relu), bf16 or f32 out. grid dim3(N/128, M/128)
template<int OUTBF, int ACT>
__global__ __launch_bounds__(256) void gemm_bf16_kernel(
    const ushort* __restrict__ A, const ushort* __restrict__ Bt,
    const float* __restrict__ bias, void* __restrict__ Cout,
    int M, int N, int K) {
    __shared__ ushort As[2 * 128 * 32];
    __shared__ ushort Bs[2 * 128 * 32];
    int m0 = blockIdx.y * 128, n0 = blockIdx.x * 128;
    GEMM_BODY_DMA_DB(A, Bt, K)
    float* Cf  = (float*)Cout;
    ushort* Cb = (ushort*)Cout;
    #pragma unroll
    for (int ni = 0; ni < 4; ++ni) {
        int cg = n0 + wc * 64 + ni * 16 + fr;
        float bv = bias ? bias[cg] : 0.0f;
        #pragma unroll
        for (int mi = 0; mi < 4; ++mi) {
            int rg = m0 + wr * 64 + mi * 16 + kq * 4;
            #pragma unroll
            for (int r = 0; r < 4; ++r) {
                float v = acc[mi][ni][r] + bv;
                if (ACT) v = fmaxf(v, 0.0f);
                if (OUTBF) Cb[(size_t)(rg + r) * N + cg] = f2b(v);
                else       Cf[(size_t)(rg + r) * N + cg] = v;
            }
        }
    }
}

// split-K=4 GEMM (ow/ff2): grid dim3(N/128, M/128, 4).
__global__ __launch_bounds__(256) void gemm_splitk4_kernel(
    const ushort* __restrict__ A, const ushort* __restrict__ Bt,
    const float* __restrict__ bias,
    float* __restrict__ C0, float* __restrict__ C1,
    float* __restrict__ C2, float* __restrict__ C3,
    int N, int K) {
    __shared__ ushort As[2 * 128 * 32];
    __shared__ ushort Bs[2 * 128 * 32];
    int m0 = blockIdx.y * 128, n0 = blockIdx.x * 128;
    const int z = blockIdx.z;
    const int kext = K >> 2;
    const ushort* Az = A + (size_t)z * kext;
    const ushort* Bz = Bt + (size_t)z * kext;
    GEMM_BODY_DMA_DB2(Az, Bz, kext, K, K)
    float* Cf = (z == 0) ? C0 : (z == 1) ? C1 : (z == 2) ? C2 : C3;
    const float* bp = (z == 0) ? bias : nullptr;
    #pragma unroll
    for (int ni = 0; ni < 4; ++ni) {
        int cg = n0 + wc * 64 + ni * 16 + fr;
        float bv = bp ? bp[cg] : 0.0f;
        #pragma unroll
        for (int mi = 0; mi < 4; ++mi) {
            int rg = m0 + wr * 64 + mi * 16 + kq * 4;
            #pragma unroll
            for (int r = 0; r < 4; ++r)
                Cf[(size_t)(rg + r) * N + cg] = acc[mi][ni][r] + bv;
        }
    }
}

// QKV (blocks 0..767) + rhk (blocks 768..799) fused (R17 compaction).
__global__ __launch_bounds__(256) void qkv_rhk_kernel(
    const ushort* __restrict__ Am, const ushort* __restrict__ Ah,
    const ushort* __restrict__ Bt,
    const float* __restrict__ rwb, const float* __restrict__ rrb,
    ushort* __restrict__ Qw, ushort* __restrict__ Qr,
    ushort* __restrict__ Kg, ushort* __restrict__ Vg,
    const ushort* __restrict__ Apos, const ushort* __restrict__ Brw,
    ushort* __restrict__ rhkT) {
    __shared__ ushort As[2 * 128 * 32];
    __shared__ ushort Bs[2 * 128 * 32];
    if (blockIdx.x < 768) {
        int id = blockIdx.x;
        int m0 = (id / 24) * 128, n0 = (id % 24) * 128;
        const ushort* Aeff = (m0 < 2048) ? Am : (Ah - (size_t)2048 * DMODEL);
        GEMM_BODY_DMA_DB(Aeff, Bt, DMODEL)
        #pragma unroll
        for (int ni = 0; ni < 4; ++ni) {
            int e = n0 + wc * 64 + ni * 16 + fr;
            #pragma unroll
            for (int mi = 0; mi < 4; ++mi) {
                int rg = m0 + wr * 64 + mi * 16 + kq * 4;
                #pragma unroll
                for (int r = 0; r < 4; ++r) {
                    float v = acc[mi][ni][r];
                    int m = rg + r;
                    int b_ = m & 7, jr = m >> 3;
                    if (e < 1024) {
                        if (m >= 2048) {
                            int n_ = e >> 6, d_ = e & 63, i_ = jr - 256;
                            size_t qa = (((size_t)b_ * 16 + n_) * 256 + i_) * 64 + d_;
                            Qw[qa] = f2b(v + rwb[e]);
                            Qr[qa] = f2b(v + rrb[e]);
                        }
                    } else if (e < 2048) {
                        int e2 = e - 1024;
                        int n_ = e2 >> 6, d_ = e2 & 63;
                        Kg[(((size_t)b_ * 16 + n_) * 512 + jr) * 64 + d_] = f2b(v);
                    } else {
                        int e2 = e - 2048;
                        int n_ = e2 >> 6, d_ = e2 & 63;
                        Vg[(((size_t)b_ * 16 + n_) * 512 + jr) * 64 + d_] = f2b(v);
                    }
                }
            }
        }
    } else {
        int rid = blockIdx.x - 768;
        int m0 = (rid / 8) * 128, n0 = (rid % 8) * 128;
        GEMM_BODY_REG(Apos, Brw, DMODEL)
        #pragma unroll
        for (int ni = 0; ni < 4; ++ni) {
            int e = n0 + wc * 64 + ni * 16 + fr;
            int n_ = e >> 6, d_ = e & 63;
            #pragma unroll
            for (int mi = 0; mi < 4; ++mi) {
                int rg = m0 + wr * 64 + mi * 16 + kq * 4;
                #pragma unroll
                for (int r = 0; r < 4; ++r)
                    rhkT[((size_t)n_ * 512 + (rg + r)) * 64 + d_] = f2b(acc[mi][ni][r]);
            }
        }
    }
}

// BDfull per (b,n): Qr(256x64) @ rhkT_n(512x64)^T, rel-shift in epilogue.
__global__ __launch_bounds__(256) void bd_gemm_kernel(
    const ushort* __restrict__ QrAll, const ushort* __restrict__ rhkT,
    ushort* __restrict__ BDs) {
    __shared__ ushort As[2 * 128 * 32];
    __shared__ ushort Bs[2 * 128 * 32];
    int batch = blockIdx.z;                    // b*16+n
    const ushort* A  = QrAll + (size_t)batch * (256 * 64);
    const ushort* Bt = rhkT + (size_t)(batch & 15) * (512 * 64);
    ushort* BDb = BDs + (size_t)batch * (256 * 512);
    int m0 = blockIdx.y * 128, n0 = blockIdx.x * 128;
    GEMM_BODY_DMA_DB(A, Bt, 64)
    #pragma unroll
    for (int ni = 0; ni < 4; ++ni) {
        int rr = n0 + wc * 64 + ni * 16 + fr;
        #pragma unroll
        for (int mi = 0; mi < 4; ++mi) {
            int rg = m0 + wr * 64 + mi * 16 + kq * 4;
            #pragma unroll
            for (int r = 0; r < 4; ++r) {
                int i = rg + r;
                int j = rr + i - 255;
                if ((unsigned)j < 512u)
                    BDb[(size_t)i * 512 + j] = f2b(acc[mi][ni][r]);
            }
        }
    }
}

// ---------------- fused flash attention ----------------
__global__ __launch_bounds__(256) void fused_attn_kernel(
    const ushort* __restrict__ Qw, const ushort* __restrict__ Kg,
    const ushort* __restrict__ Vg, const ushort* __restrict__ BDs,
    ushort* __restrict__ vec) {
    __shared__ ushort Ks[64 * 72];
    __shared__ ushort Vt[64 * 72];
    __shared__ ushort Pl[4][16 * 72];
    const int qt = blockIdx.x, b = blockIdx.y, n = blockIdx.z;
    const int tid = threadIdx.x, wv = tid >> 6, lane = tid & 63;
    const int fr = lane & 15, kq = lane >> 4;
    const int q0 = qt * 64;
    const size_t bn = (size_t)b * 16 + n;
    const ushort* Qb  = Qw + bn * 256 * 64;
    const ushort* Kb  = Kg + bn * 512 * 64;
    const ushort* Vb  = Vg + bn * 512 * 64;
    const ushort* BDb = BDs + bn * 256 * 512;
    bf16x8 aq0, aq1;
    {
        const ushort* qp = Qb + (size_t)(q0 + wv * 16 + fr) * 64 + kq * 8;
        aq0 = *(const bf16x8*)qp;
        aq1 = *(const bf16x8*)(qp + 32);
    }
    f32x4 O[4] = {};
    float m_r[4], l_r[4];
    #pragma unroll
    for (int r = 0; r < 4; ++r) { m_r[r] = -INFINITY; l_r[r] = 0.0f; }
    const int NT = qt + 5;
    const int krow = tid >> 2, kseg = tid & 3;
    const int vrow = tid & 63, vseg0 = tid >> 6;
    for (int jt = 0; jt < NT; ++jt) {
        __syncthreads();
        {
            const ushort* src = Kb + (size_t)(jt * 64 + krow) * 64 + kseg * 16;
            *(float4*)&Ks[krow * 72 + kseg * 16]     = *(const float4*)src;
            *(float4*)&Ks[krow * 72 + kseg * 16 + 8] = *(const float4*)(src + 8);
        }
        #pragma unroll
        for (int it = 0; it < 2; ++it) {
            int seg = vseg0 + it * 4;
            const ushort* src = Vb + (size_t)(jt * 64 + vrow) * 64 + seg * 8;
            bf16x8 v = *(const bf16x8*)src;
            #pragma unroll
            for (int q = 0; q < 8; ++q)
                Vt[(seg * 8 + q) * 72 + vrow] = (ushort)v[q];
        }
        __syncthreads();
        f32x4 S[4] = {};
        #pragma unroll
        for (int cb = 0; cb < 4; ++cb) {
            const ushort* kp = &Ks[(cb * 16 + fr) * 72 + kq * 8];
            bf16x8 b0 = *(const bf16x8*)kp;
            bf16x8 b1 = *(const bf16x8*)(kp + 32);
            S[cb] = __builtin_amdgcn_mfma_f32_16x16x32_bf16(aq0, b0, S[cb], 0, 0, 0);
            S[cb] = __builtin_amdgcn_mfma_f32_16x16x32_bf16(aq1, b1, S[cb], 0, 0, 0);
        }
        #pragma unroll
        for (int cb = 0; cb < 4; ++cb) {
            int j = jt * 64 + cb * 16 + fr;
            #pragma unroll
            for (int r = 0; r < 4; ++r) {
                int i = q0 + wv * 16 + kq * 4 + r;
                float bd = b2f(BDb[(size_t)i * 512 + j]);
                float s = (S[cb][r] + bd) * 0.125f;
                S[cb][r] = (j <= i + 256) ? s : -1e30f;
            }
        }
        float sc[4];
        #pragma unroll
        for (int r = 0; r < 4; ++r) {
            float t = fmaxf(fmaxf(S[0][r], S[1][r]), fmaxf(S[2][r], S[3][r]));
            t = fmaxf(t, __shfl_xor(t, 1));
            t = fmaxf(t, __shfl_xor(t, 2));
            t = fmaxf(t, __shfl_xor(t, 4));
            t = fmaxf(t, __shfl_xor(t, 8));
            float mn = fmaxf(m_r[r], t);
            sc[r] = __expf(m_r[r] - mn);
            m_r[r] = mn;
        }
        float ts[4] = {0.0f, 0.0f, 0.0f, 0.0f};
        #pragma unroll
        for (int cb = 0; cb < 4; ++cb)
            #pragma unroll
            for (int r = 0; r < 4; ++r) {
                float p = __expf(S[cb][r] - m_r[r]);
                S[cb][r] = p;
                ts[r] += p;
            }
        #pragma unroll
        for (int r = 0; r < 4; ++r) {
            float t = ts[r];
            t += __shfl_xor(t, 1);
            t += __shfl_xor(t, 2);
            t += __shfl_xor(t, 4);
            t += __shfl_xor(t, 8);
            l_r[r] = l_r[r] * sc[r] + t;
            #pragma unroll
            for (int ob = 0; ob < 4; ++ob) O[ob][r] *= sc[r];
        }
        ushort* P = &Pl[wv][0];
        #pragma unroll
        for (int cb = 0; cb < 4; ++cb)
            #pragma unroll
            for (int r = 0; r < 4; ++r)
                P[(kq * 4 + r) * 72 + cb * 16 + fr] = f2b(S[cb][r]);
        asm volatile("s_waitcnt lgkmcnt(0)" ::: "memory");
        bf16x8 pa0 = *(const bf16x8*)&P[fr * 72 + kq * 8];
        bf16x8 pa1 = *(const bf16x8*)&P[fr * 72 + 32 + kq * 8];
        #pragma unroll
        for (int ob = 0; ob < 4; ++ob) {
            const ushort* vp = &Vt[(ob * 16 + fr) * 72 + kq * 8];
            bf16x8 v0 = *(const bf16x8*)vp;
            bf16x8 v1 = *(const bf16x8*)(vp + 32);
            O[ob] = __builtin_amdgcn_mfma_f32_16x16x32_bf16(pa0, v0, O[ob], 0, 0, 0);
            O[ob] = __builtin_amdgcn_mfma_f32_16x16x32_bf16(pa1, v1, O[ob], 0, 0, 0);
        }
    }
    #pragma unroll
    for (int r = 0; r < 4; ++r) {
        float inv = 1.0f / l_r[r];
        int i = q0 + wv * 16 + kq * 4 + r;
        size_t base = ((size_t)i * 8 + b) * 1024 + n * 64;
        #pragma unroll
        for (int ob = 0; ob < 4; ++ob)
            vec[base + ob * 16 + fr] = f2b(O[ob][r] * inv);
    }
}

// logits GEMM + fused per-token (max, sumexp) + fused tgt dot-products.
__global__ __launch_bounds__(256) void logits_lse_kernel(
    const ushort* __restrict__ A, const ushort* __restrict__ Bt,
    const float* __restrict__ ob, float* __restrict__ pmax, float* __restrict__ psum,
    const float* __restrict__ hf, const float* __restrict__ Wf,
    const int* __restrict__ target, float* __restrict__ tgtout) {
    __shared__ ushort As[128 * 32];
    __shared__ ushort Bs[128 * 32];
    __shared__ float redm[2][128], reds[2][128];
    if (blockIdx.x >= 4000) {
        int wv2 = threadIdx.x >> 6, lane2 = threadIdx.x & 63;
        int t = (blockIdx.x - 4000) * 4 + wv2;
        int row = target[t];
        const float* hp = hf + (size_t)t * DMODEL;
        const float* wp = Wf + (size_t)row * DMODEL;
        float s = 0.0f;
        for (int d = lane2; d < DMODEL; d += 64) s += hp[d] * wp[d];
        for (int o = 32; o > 0; o >>= 1) s += __shfl_down(s, o);
        if (lane2 == 0) tgtout[t] = s + ob[row];
        return;
    }
    int logical = xcd_swizzle(blockIdx.x, 4000);
    int bx = logical / 16;       // vocab tile (slow)
    int by = logical % 16;       // token tile (fast)
    int m0 = bx * 128;           // vocab
    int n0 = by * 128;           // tokens
    GEMM_BODY_DMA_SB(A, Bt, DMODEL)
    int t0 = n0;
    #pragma unroll
    for (int ni = 0; ni < 4; ++ni) {
        float vals[16];
        float vmax = -1e30f;
        #pragma unroll
        for (int mi = 0; mi < 4; ++mi) {
            int rg = m0 + wr * 64 + mi * 16 + kq * 4;
            float4 ob4 = *(const float4*)&ob[rg];
            float o4[4] = {ob4.x, ob4.y, ob4.z, ob4.w};
            #pragma unroll
            for (int r = 0; r < 4; ++r) {
                float v = acc[mi][ni][r] + o4[r];
                vals[mi * 4 + r] = v;
                vmax = fmaxf(vmax, v);
            }
        }
        vmax = fmaxf(vmax, __shfl_xor(vmax, 16));
        vmax = fmaxf(vmax, __shfl_xor(vmax, 32));
        float s = 0.0f;
        #pragma unroll
        for (int q = 0; q < 16; ++q) s += __expf(vals[q] - vmax);
        s += __shfl_xor(s, 16);
        s += __shfl_xor(s, 32);
        if (kq == 0) {
            redm[wr][wc * 64 + ni * 16 + fr] = vmax;
            reds[wr][wc * 64 + ni * 16 + fr] = s;
        }
    }
    __syncthreads();
    if (tid < 128) {
        float ma = redm[0][tid], mb = redm[1][tid];
        float m = fmaxf(ma, mb);
        float s = reds[0][tid] * __expf(ma - m) + reds[1][tid] * __expf(mb - m);
        pmax[(size_t)(t0 + tid) * VTILES + bx] = m;
        psum[(size_t)(t0 + tid) * VTILES + bx] = s;
    }
}

// h = LN(act(x0+x1+x2+x3) + h)*g + b, writes fp32 h and bf16 copy.
template<int RELU>
__global__ __launch_bounds__(256) void ln_combine4_kernel(const float* __restrict__ x0,
    const float* __restrict__ x1, const float* __restrict__ x2,
    const float* __restrict__ x3, float* __restrict__ h, const float* __restrict__ g,
    const float* __restrict__ bb, ushort* __restrict__ hb) {
    int t = blockIdx.x, tid = threadIdx.x;
    __shared__ float rs[256], rq[256];
    float v[4];
    float s = 0.0f, sq = 0.0f;
    for (int u = 0; u < 4; ++u) {
        int d = tid + u * 256;
        size_t idx = (size_t)t * DMODEL + d;
        float xx = (x0[idx] + x1[idx]) + (x2[idx] + x3[idx]);
        if (RELU) xx = fmaxf(xx, 0.0f);
        float val = xx + h[idx];
        v[u] = val; s += val; sq += val * val;
    }
    rs[tid] = s; rq[tid] = sq;
    __syncthreads();
    for (int st = 128; st > 0; st >>= 1) {
        if (tid < st) { rs[tid] += rs[tid + st]; rq[tid] += rq[tid + st]; }
        __syncthreads();
    }
    float mean = rs[0] * (1.0f / DMODEL);
    float var = rq[0] * (1.0f / DMODEL) - mean * mean;
    float r = rsqrtf(var + 1e-3f);
    for (int u = 0; u < 4; ++u) {
        int d = tid + u * 256;
        float o = (v[u] - mean) * r * g[d] + bb[d];
        h[(size_t)t * DMODEL + d] = o;
        hb[(size_t)t * DMODEL + d] = f2b(o);
    }
}

// ---------------- final loss pieces ----------------

// 512 blocks x 256 threads; wave wv handles token t = blk*4 + wv.
__global__ __launch_bounds__(256) void lse_kernel(const float* __restrict__ pmax,
    const float* __restrict__ psum, float* __restrict__ lse) {
    int wv = threadIdx.x >> 6, lane = threadIdx.x & 63;
    int t = blockIdx.x * 4 + wv;
    const float* pm = pmax + (size_t)t * VTILES;
    const float* ps = psum + (size_t)t * VTILES;
    float m = -1e30f;
    for (int c = lane; c < VTILES; c += 64) m = fmaxf(m, pm[c]);
    for (int o = 32; o > 0; o >>= 1) m = fmaxf(m, __shfl_xor(m, o));
    float s = 0.0f;
    for (int c = lane; c < VTILES; c += 64) s += ps[c] * expf(pm[c] - m);
    for (int o = 32; o > 0; o >>= 1) s += __shfl_xor(s, o);
    if (lane == 0) lse[t] = m + logf(s);
}

__global__ __launch_bounds__(256) void loss_kernel(const float* __restrict__ lse,
    const float* __restrict__ tgt, const float* __restrict__ vm, float* __restrict__ out) {
    __shared__ float red[256];
    int tid = threadIdx.x;
    float s = 0.0f;
    for (int t = tid; t < NTOK; t += 256) s += (lse[t] - tgt[t]) * vm[t];
    red[tid] = s;
    __syncthreads();
    for (int st = 128; st > 0; st >>= 1) {
        if (tid < st) red[tid] += red[tid + st];
        __syncthreads();
    }
    if (tid == 0) out[0] = red[0] * (1.0f / NTOK);
}

// ---------------- launch ----------------
extern "C" void kernel_launch(void* const* d_in, const int* in_sizes, int n_in,
                              void* d_out, int out_size, void* d_ws, size_t ws_size,
                              hipStream_t stream) {
    const int*   dec_inp   = (const int*)  d_in[0];
    const int*   target    = (const int*)  d_in[1];
    const float* valid     = (const float*)d_in[2];
    const float* mems      = (const float*)d_in[3];
    const float* vocab_emb = (const float*)d_in[4];
    const float* out_w     = (const float*)d_in[5];
    const float* out_b     = (const float*)d_in[6];
    const float* qkv_w     = (const float*)d_in[7];
    const float* r_w       = (const float*)d_in[8];
    const float* o_w       = (const float*)d_in[9];
    const float* ln1_g     = (const float*)d_in[10];
    const float* ln1_b     = (const float*)d_in[11];
    const float* ff_w1     = (const float*)d_in[12];
    const float* ff_b1     = (const float*)d_in[13];
    const float* ff_w2     = (const float*)d_in[14];
    const float* ff_b2     = (const float*)d_in[15];
    const float* ln2_g     = (const float*)d_in[16];
    const float* ln2_b     = (const float*)d_in[17];
    const float* r_w_bias  = (const float*)d_in[18];
    const float* r_r_bias  = (const float*)d_in[19];

    float* ws = (float*)d_ws;
    float*  h      = ws + O_H;
    ushort* hbf    = (ushort*)(ws + O_HBF);
    ushort* posbf  = (ushort*)(ws + O_POSBF);
    ushort* qkvt   = (ushort*)(ws + O_QKVT);
    ushort* rwt    = (ushort*)(ws + O_RWT);
    ushort* owt    = (ushort*)(ws + O_OWT);
    ushort* ffw1t  = (ushort*)(ws + O_FFW1T);
    ushort* ffw2t  = (ushort*)(ws + O_FFW2T);
    ushort* membf  = (ushort*)(ws + O_MEMBF);
    ushort* qwv    = (ushort*)(ws + O_QW);
    ushort* qrv    = (ushort*)(ws + O_QR);
    ushort* kg     = (ushort*)(ws + O_KG);
    ushort* vg     = (ushort*)(ws + O_VG);
    ushort* rhkT   = (ushort*)(ws + O_RHKT);
    ushort* vecbf  = (ushort*)(ws + O_VECBF);
    float*  tattn  = ws + O_TATTN;
    ushort* bds    = (ushort*)(ws + O_BDS);
    float*  owp0   = ws + O_BDS;
    float*  owp1   = ws + O_BDS + 2097152;
    float*  owp2   = ws + O_BDS + 4194304;
    float*  owp3   = ws + O_BDS + 6291456;
    ushort* t1bf   = (ushort*)(ws + O_T1BF);
    float*  t2     = ws + O_T2;
    float*  t2b    = ws + O_T2B;
    float*  ffp2   = tattn;
    float*  ffp3   = (float*)(ws + O_KG);
    ushort* outwbf = (ushort*)(ws + O_OUTWBF);
    float*  pmax   = ws + O_PMAX;
    float*  psum   = ws + O_PSUM;
    float*  lse    = ws + O_LSE;
    float*  tgt    = ws + O_TGT;

    prep_all_kernel<<<33280, 256, 0, stream>>>(
        qkv_w, r_w, o_w, ff_w1, ff_w2, qkvt, rwt, owt, ffw1t, ffw2t,
        dec_inp, vocab_emb, h, hbf, posbf, mems, membf);

    for (int l = 0; l < NLAYER; ++l) {
        qkv_rhk_kernel<<<800, 256, 0, stream>>>(
            membf + (size_t)l * 2097152, hbf,
            qkvt + (size_t)l * 3072 * DMODEL, r_w_bias, r_r_bias, qwv, qrv, kg, vg,
            posbf, rwt + (size_t)l * DMODEL * DMODEL, rhkT);
        bd_gemm_kernel<<<dim3(4, 2, 128), 256, 0, stream>>>(qrv, rhkT, bds);
        fused_attn_kernel<<<dim3(4, BSZ, NHEAD), 256, 0, stream>>>(qwv, kg, vg, bds, vecbf);
        gemm_splitk4_kernel<<<dim3(8, 16, 4), 256, 0, stream>>>(
            vecbf, owt + (size_t)l * DMODEL * DMODEL, nullptr,
            owp0, owp1, owp2, owp3, DMODEL, DMODEL);
        ln_combine4_kernel<0><<<NTOK, 256, 0, stream>>>(
            owp0, owp1, owp2, owp3, h, ln1_g + l * DMODEL, ln1_b + l * DMODEL, hbf);
        gemm_bf16_kernel<1, 1><<<dim3(32, 16), 256, 0, stream>>>(
            hbf, ffw1t + (size_t)l * DINNER * DMODEL, ff_b1 + (size_t)l * DINNER, t1bf, NTOK, DINNER, DMODEL);
        gemm_splitk4_kernel<<<dim3(8, 16, 4), 256, 0, stream>>>(
            t1bf, ffw2t + (size_t)l * DMODEL * DINNER, ff_b2 + (size_t)l * DMODEL,
            t2, t2b, ffp2, ffp3, DMODEL, DINNER);
        ln_combine4_kernel<1><<<NTOK, 256, 0, stream>>>(
            t2, t2b, ffp2, ffp3, h, ln2_g + l * DMODEL, ln2_b + l * DMODEL, hbf);
    }

    convert_bf16_kernel<<<32000, 256, 0, stream>>>(out_w, outwbf);
    logits_lse_kernel<<<4512, 256, 0, stream>>>(
        outwbf, hbf, out_b, pmax, psum, h, out_w, target, tgt);
    lse_kernel<<<512, 256, 0, stream>>>(pmax, psum, lse);
    loss_kernel<<<1, 256, 0, stream>>>(lse, tgt, valid, (float*)d_out);
}

// Round 25
// 645.348 us; speedup vs baseline: 1.1229x; 1.0153x over previous
//
#include <hip/hip_runtime.h>
#include <hip/hip_bf16.h>
#include <math.h>

// ---------------- problem constants ----------------
#define QLEN 256
#define MLEN 256
#define KLEN 512
#define BSZ 8
#define DMODEL 1024
#define NHEAD 16
#define DHEAD 64
#define DINNER 4096
#define NTOKEN 32000
#define NLAYER 2
#define NTOK 2048          // QLEN*BSZ
#define VTILES 250         // 32000/128
#define LPAD 40            // reg-staged LDS row pitch (R3-proven)

typedef __attribute__((ext_vector_type(8))) short bf16x8;
typedef __attribute__((ext_vector_type(4))) float f32x4;

__device__ __forceinline__ float b2f(ushort u) { return __uint_as_float(((unsigned)u) << 16); }
__device__ __forceinline__ ushort f2b(float x) {
  unsigned u = __float_as_uint(x);
  return (ushort)((u + 0x7fffu + ((u >> 16) & 1u)) >> 16);
}

// async global->LDS, 16B per lane. lds ptr must be wave-uniform base; HW adds lane*16.
__device__ __forceinline__ void gload16(const ushort* g, ushort* l) {
    __builtin_amdgcn_global_load_lds(
        (const __attribute__((address_space(1))) unsigned int*)(g),
        (__attribute__((address_space(3))) unsigned int*)(l), 16, 0, 0);
}

// ---------------- workspace layout (float offsets) ----------------
static const size_t O_H      = 0;                    // h fp32          2,097,152
static const size_t O_HBF    = 2097152;              // h bf16          1,048,576
static const size_t O_POSBF  = 3145728;              // pos bf16          262,144
static const size_t O_QKVT   = 3407872;              // 2x 3072x1024 bf 3,145,728
static const size_t O_RWT    = O_QKVT + 3145728;     // 2x 1024x1024 bf 1,048,576
static const size_t O_OWT    = O_RWT + 1048576;      // 2x 1024x1024 bf 1,048,576
static const size_t O_FFW1T  = O_OWT + 1048576;      // 2x 4096x1024 bf 4,194,304
static const size_t O_FFW2T  = O_FFW1T + 4194304;    // 2x 1024x4096 bf 4,194,304
static const size_t O_SCR    = O_FFW2T + 4194304;    // = 17,039,360
static const size_t O_MEMBF  = O_SCR;                // 2x 2048x1024 bf 2,097,152
static const size_t O_QW     = O_SCR + 2097152;      // 8*16*256*64 bf  1,048,576
static const size_t O_QR     = O_QW + 1048576;       //                 1,048,576
static const size_t O_KG     = O_QR + 1048576;       // 8*16*512*64 bf  2,097,152
static const size_t O_VG     = O_KG + 2097152;       //                 2,097,152
static const size_t O_RHKT   = O_SCR + 8388608;      // 16*512*64 bf      262,144
static const size_t O_VECBF  = O_SCR + 8650752;      // 2048x1024 bf    1,048,576
static const size_t O_TATTN  = O_SCR + 9699328;      // 2048x1024 f32   2,097,152
static const size_t O_BDS    = O_SCR + 11796480;     // 128*256*512 bf  (span 8,388,608 floats)
static const size_t O_T1BF   = O_BDS;
static const size_t O_T2     = O_BDS + 4194304;
static const size_t O_T2B    = O_T2 + 2097152;
static const size_t O_OUTWBF = O_SCR;                // 32000x1024 bf  16,384,000 (logits phase)
static const size_t O_PMAX   = O_SCR + 16384000;     // 2048*250          512,000
static const size_t O_PSUM   = O_PMAX + 512000;      //                   512,000
static const size_t O_LSE    = O_PSUM + 512000;      // 2048
static const size_t O_TGT    = O_LSE + 2048;         // 2048

// ---------------- fused prep kernel (R17/R19/R20 compaction) ----------------
// Blocks 0..26623: 10 weight transposes (2 layers x 5 weights).
// Blocks 26624..33279: embed (2048) + posemb (512) + mems->bf16 (4096).
__global__ __launch_bounds__(256) void prep_all_kernel(
    const float* __restrict__ qkv_w, const float* __restrict__ r_w,
    const float* __restrict__ o_w, const float* __restrict__ ff_w1,
    const float* __restrict__ ff_w2,
    ushort* __restrict__ qkvt, ushort* __restrict__ rwt, ushort* __restrict__ owt,
    ushort* __restrict__ ffw1t, ushort* __restrict__ ffw2t,
    const int* __restrict__ dec, const float* __restrict__ emb,
    float* __restrict__ h, ushort* __restrict__ hb,
    ushort* __restrict__ pe, const float* __restrict__ mems,
    ushort* __restrict__ membf) {
    __shared__ float tile[32][33];
    int id = blockIdx.x;
    if (id >= 26624) {
        id -= 26624;
        if (id < 2048) {
            int t = id;
            int tok = dec[t];
            const float* src = emb + (size_t)tok * DMODEL;
            float* dst = h + (size_t)t * DMODEL;
            ushort* dstb = hb + (size_t)t * DMODEL;
            for (int u = 0; u < 4; ++u) {
                int d = threadIdx.x + u * 256;
                float v = src[d] * 32.0f;
                dst[d] = v;
                dstb[d] = f2b(v);
            }
        } else if (id < 2560) {
            int r = id - 2048;
            float pos = (float)(KLEN - 1 - r);
            for (int u = 0; u < 2; ++u) {
                int dp = threadIdx.x + u * 256;
                float inv = expf(-(float)dp * (9.210340371976184f / 512.0f));
                float ang = pos * inv;
                pe[(size_t)r * DMODEL + dp]       = f2b(sinf(ang));
                pe[(size_t)r * DMODEL + 512 + dp] = f2b(cosf(ang));
            }
        } else {
            size_t i = (size_t)(id - 2560) * 256 + threadIdx.x;
            float4 v = ((const float4*)mems)[i];
            ushort4 o;
            o.x = f2b(v.x); o.y = f2b(v.y); o.z = f2b(v.z); o.w = f2b(v.w);
            ((ushort4*)membf)[i] = o;
        }
        return;
    }
    int l = (id >= 13312) ? 1 : 0;
    id -= l * 13312;
    const float* W; ushort* Wt; int K, N, nbx;
    if (id < 3072) {
        W = qkv_w + (size_t)l * DMODEL * 3072; Wt = qkvt + (size_t)l * 3072 * DMODEL;
        K = DMODEL; N = 3072; nbx = 96;
    } else if (id < 4096) {
        id -= 3072;
        W = r_w + (size_t)l * DMODEL * DMODEL; Wt = rwt + (size_t)l * DMODEL * DMODEL;
        K = DMODEL; N = DMODEL; nbx = 32;
    } else if (id < 5120) {
        id -= 4096;
        W = o_w + (size_t)l * DMODEL * DMODEL; Wt = owt + (size_t)l * DMODEL * DMODEL;
        K = DMODEL; N = DMODEL; nbx = 32;
    } else if (id < 9216) {
        id -= 5120;
        W = ff_w1 + (size_t)l * DMODEL * DINNER; Wt = ffw1t + (size_t)l * DINNER * DMODEL;
        K = DMODEL; N = DINNER; nbx = 128;
    } else {
        id -= 9216;
        W = ff_w2 + (size_t)l * DINNER * DMODEL; Wt = ffw2t + (size_t)l * DMODEL * DINNER;
        K = DINNER; N = DMODEL; nbx = 32;
    }
    int bx = id % nbx, by = id / nbx;
    int n0 = bx * 32, k0 = by * 32;
    int tx = threadIdx.x & 31, ty = threadIdx.x >> 5;
    for (int u = 0; u < 4; ++u)
        tile[ty + u * 8][tx] = W[(size_t)(k0 + ty + u * 8) * N + n0 + tx];
    __syncthreads();
    for (int u = 0; u < 4; ++u)
        Wt[(size_t)(n0 + ty + u * 8) * K + k0 + tx] = f2b(tile[tx][ty + u * 8]);
}

__global__ __launch_bounds__(256) void convert_bf16_kernel(const float* __restrict__ W,
    ushort* __restrict__ Wb) {
    size_t i = (size_t)blockIdx.x * 256 + threadIdx.x;
    float4 v = ((const float4*)W)[i];
    ushort4 o;
    o.x = f2b(v.x); o.y = f2b(v.y); o.z = f2b(v.z); o.w = f2b(v.w);
    ((ushort4*)Wb)[i] = o;
}

// XCD-aware bijective swizzle for nwg % 8 == 0 (contiguous logical chunk per XCD)
__device__ __forceinline__ int xcd_swizzle(int bid, int nwg) {
    int cpx = nwg >> 3;
    return (bid & 7) * cpx + (bid >> 3);
}

// ------- GEMM body, DMA-staged, 2-phase double-buffer, general strides.
#define GEMM_BODY_DMA_DB2(APTR, BPTR, KEXT, LDA, LDB)                          \
    const int tid = threadIdx.x;                                               \
    const int wave = tid >> 6, lane = tid & 63;                                \
    const int wr = wave >> 1, wc = wave & 1;                                   \
    const int fr = lane & 15, kq = lane >> 4;                                  \
    const int srow = wave * 16 + (lane >> 2);                                  \
    const int scol = 8 * ((lane & 3) ^ ((lane >> 3) & 3));                     \
    const int rsw  = 8 * (kq ^ ((fr >> 1) & 3));                               \
    const ushort* Ap = (APTR) + (size_t)(m0 + srow) * (LDA) + scol;            \
    const ushort* Bp = (BPTR) + (size_t)(n0 + srow) * (LDB) + scol;            \
    ushort* Al = &As[wave * 512];                                              \
    ushort* Bl = &Bs[wave * 512];                                              \
    const ushort* Ard = &As[(wr * 64 + fr) * 32 + rsw];                        \
    const ushort* Brd = &Bs[(wc * 64 + fr) * 32 + rsw];                        \
    const size_t halfA = (size_t)64 * (LDA);                                   \
    const size_t halfB = (size_t)64 * (LDB);                                   \
    const int nk = (KEXT) / 32;                                                \
    gload16(Ap, Al);                                                           \
    gload16(Ap + halfA, Al + 2048);                                            \
    gload16(Bp, Bl);                                                           \
    gload16(Bp + halfB, Bl + 2048);                                            \
    f32x4 acc[4][4] = {};                                                      \
    int cur = 0;                                                               \
    for (int t = 0; t < nk; ++t) {                                             \
        __syncthreads();                                                       \
        if (t + 1 < nk) {                                                      \
            const int kn = (t + 1) * 32;                                       \
            const int nxt = (cur ^ 1) * 4096;                                  \
            gload16(Ap + kn, Al + nxt);                                        \
            gload16(Ap + kn + halfA, Al + nxt + 2048);                         \
            gload16(Bp + kn, Bl + nxt);                                        \
            gload16(Bp + kn + halfB, Bl + nxt + 2048);                         \
        }                                                                      \
        const ushort* Ardc = Ard + cur * 4096;                                 \
        const ushort* Brdc = Brd + cur * 4096;                                 \
        bf16x8 af[4], bfr[4];                                                  \
        _Pragma("unroll")                                                      \
        for (int i = 0; i < 4; ++i) af[i]  = *(const bf16x8*)(Ardc + i * 16 * 32); \
        _Pragma("unroll")                                                      \
        for (int i = 0; i < 4; ++i) bfr[i] = *(const bf16x8*)(Brdc + i * 16 * 32); \
        _Pragma("unroll")                                                      \
        for (int mi = 0; mi < 4; ++mi)                                         \
            _Pragma("unroll")                                                  \
            for (int ni = 0; ni < 4; ++ni)                                     \
                acc[mi][ni] = __builtin_amdgcn_mfma_f32_16x16x32_bf16(         \
                    af[mi], bfr[ni], acc[mi][ni], 0, 0, 0);                    \
        cur ^= 1;                                                              \
    }

#define GEMM_BODY_DMA_DB(APTR, BPTR, KDIM) GEMM_BODY_DMA_DB2(APTR, BPTR, KDIM, KDIM, KDIM)

// ------- GEMM body, DMA-staged single-buffer BK=32 (logits best) --
#define GEMM_BODY_DMA_SB(APTR, BPTR, KDIM)                                     \
    const int tid = threadIdx.x;                                               \
    const int wave = tid >> 6, lane = tid & 63;                                \
    const int wr = wave >> 1, wc = wave & 1;                                   \
    const int fr = lane & 15, kq = lane >> 4;                                  \
    const int srow = wave * 16 + (lane >> 2);                                  \
    const int scol = 8 * ((lane & 3) ^ ((lane >> 3) & 3));                     \
    const int rsw  = 8 * (kq ^ ((fr >> 1) & 3));                               \
    const ushort* Ap = (APTR) + (size_t)(m0 + srow) * (KDIM) + scol;           \
    const ushort* Bp = (BPTR) + (size_t)(n0 + srow) * (KDIM) + scol;           \
    ushort* Al = &As[wave * 512];                                              \
    ushort* Bl = &Bs[wave * 512];                                              \
    const ushort* Ard = &As[(wr * 64 + fr) * 32 + rsw];                        \
    const ushort* Brd = &Bs[(wc * 64 + fr) * 32 + rsw];                        \
    const size_t halfstep = (size_t)64 * (KDIM);                               \
    f32x4 acc[4][4] = {};                                                      \
    for (int k0 = 0; k0 < (KDIM); k0 += 32) {                                  \
        __syncthreads();                                                       \
        gload16(Ap + k0, Al);                                                  \
        gload16(Ap + k0 + halfstep, Al + 2048);                                \
        gload16(Bp + k0, Bl);                                                  \
        gload16(Bp + k0 + halfstep, Bl + 2048);                                \
        __syncthreads();                                                       \
        bf16x8 af[4], bfr[4];                                                  \
        _Pragma("unroll")                                                      \
        for (int i = 0; i < 4; ++i) af[i]  = *(const bf16x8*)(Ard + i * 16 * 32); \
        _Pragma("unroll")                                                      \
        for (int i = 0; i < 4; ++i) bfr[i] = *(const bf16x8*)(Brd + i * 16 * 32); \
        _Pragma("unroll")                                                      \
        for (int mi = 0; mi < 4; ++mi)                                         \
            _Pragma("unroll")                                                  \
            for (int ni = 0; ni < 4; ++ni)                                     \
                acc[mi][ni] = __builtin_amdgcn_mfma_f32_16x16x32_bf16(         \
                    af[mi], bfr[ni], acc[mi][ni], 0, 0, 0);                    \
    }

// ------- GEMM body, register-staged (R3-proven, pitch LPAD=40) -------
#define GEMM_BODY_REG(APTR, BPTR, KDIM)                                        \
    const int tid = threadIdx.x;                                               \
    const int wave = tid >> 6, lane = tid & 63;                                \
    const int wr = wave >> 1, wc = wave & 1;                                   \
    const int srow = tid >> 1, shalf = tid & 1;                                \
    const ushort* Ap = (APTR) + (size_t)(m0 + srow) * (KDIM) + shalf * 16;     \
    const ushort* Bp = (BPTR) + (size_t)(n0 + srow) * (KDIM) + shalf * 16;     \
    ushort* Asw = &As[srow * LPAD + shalf * 16];                               \
    ushort* Bsw = &Bs[srow * LPAD + shalf * 16];                               \
    const int fr = lane & 15, kq = lane >> 4;                                  \
    const ushort* Ard = &As[(wr * 64 + fr) * LPAD + kq * 8];                   \
    const ushort* Brd = &Bs[(wc * 64 + fr) * LPAD + kq * 8];                   \
    f32x4 acc[4][4] = {};                                                      \
    for (int k0 = 0; k0 < (KDIM); k0 += 32) {                                  \
        float4 a0 = *(const float4*)(Ap + k0);                                 \
        float4 a1 = *(const float4*)(Ap + k0 + 8);                             \
        float4 b0 = *(const float4*)(Bp + k0);                                 \
        float4 b1 = *(const float4*)(Bp + k0 + 8);                             \
        *(float4*)(Asw)     = a0; *(float4*)(Asw + 8) = a1;                    \
        *(float4*)(Bsw)     = b0; *(float4*)(Bsw + 8) = b1;                    \
        __syncthreads();                                                       \
        bf16x8 af[4], bfr[4];                                                  \
        _Pragma("unroll")                                                      \
        for (int i = 0; i < 4; ++i) af[i]  = *(const bf16x8*)(Ard + i * 16 * LPAD); \
        _Pragma("unroll")                                                      \
        for (int i = 0; i < 4; ++i) bfr[i] = *(const bf16x8*)(Brd + i * 16 * LPAD); \
        _Pragma("unroll")                                                      \
        for (int mi = 0; mi < 4; ++mi)                                         \
            _Pragma("unroll")                                                  \
            for (int ni = 0; ni < 4; ++ni)                                     \
                acc[mi][ni] = __builtin_amdgcn_mfma_f32_16x16x32_bf16(         \
                    af[mi], bfr[ni], acc[mi][ni], 0, 0, 0);                    \
        __syncthreads();                                                       \
    }

// generic: C = A * Bt^T (+bias)(+relu), bf16 or f32 out. grid dim3(N/128, M/128)
template<int OUTBF, int ACT>
__global__ __launch_bounds__(256) void gemm_bf16_kernel(
    const ushort* __restrict__ A, const ushort* __restrict__ Bt,
    const float* __restrict__ bias, void* __restrict__ Cout,
    int M, int N, int K) {
    __shared__ ushort As[2 * 128 * 32];
    __shared__ ushort Bs[2 * 128 * 32];
    int m0 = blockIdx.y * 128, n0 = blockIdx.x * 128;
    GEMM_BODY_DMA_DB(A, Bt, K)
    float* Cf  = (float*)Cout;
    ushort* Cb = (ushort*)Cout;
    #pragma unroll
    for (int ni = 0; ni < 4; ++ni) {
        int cg = n0 + wc * 64 + ni * 16 + fr;
        float bv = bias ? bias[cg] : 0.0f;
        #pragma unroll
        for (int mi = 0; mi < 4; ++mi) {
            int rg = m0 + wr * 64 + mi * 16 + kq * 4;
            #pragma unroll
            for (int r = 0; r < 4; ++r) {
                float v = acc[mi][ni][r] + bv;
                if (ACT) v = fmaxf(v, 0.0f);
                if (OUTBF) Cb[(size_t)(rg + r) * N + cg] = f2b(v);
                else       Cf[(size_t)(rg + r) * N + cg] = v;
            }
        }
    }
}

// split-K=4 GEMM (ow/ff2): grid dim3(N/128, M/128, 4).
__global__ __launch_bounds__(256) void gemm_splitk4_kernel(
    const ushort* __restrict__ A, const ushort* __restrict__ Bt,
    const float* __restrict__ bias,
    float* __restrict__ C0, float* __restrict__ C1,
    float* __restrict__ C2, float* __restrict__ C3,
    int N, int K) {
    __shared__ ushort As[2 * 128 * 32];
    __shared__ ushort Bs[2 * 128 * 32];
    int m0 = blockIdx.y * 128, n0 = blockIdx.x * 128;
    const int z = blockIdx.z;
    const int kext = K >> 2;
    const ushort* Az = A + (size_t)z * kext;
    const ushort* Bz = Bt + (size_t)z * kext;
    GEMM_BODY_DMA_DB2(Az, Bz, kext, K, K)
    float* Cf = (z == 0) ? C0 : (z == 1) ? C1 : (z == 2) ? C2 : C3;
    const float* bp = (z == 0) ? bias : nullptr;
    #pragma unroll
    for (int ni = 0; ni < 4; ++ni) {
        int cg = n0 + wc * 64 + ni * 16 + fr;
        float bv = bp ? bp[cg] : 0.0f;
        #pragma unroll
        for (int mi = 0; mi < 4; ++mi) {
            int rg = m0 + wr * 64 + mi * 16 + kq * 4;
            #pragma unroll
            for (int r = 0; r < 4; ++r)
                Cf[(size_t)(rg + r) * N + cg] = acc[mi][ni][r] + bv;
        }
    }
}

// QKV (blocks 0..639) + rhk (blocks 640..671) fused.
// R25: dead-block elimination -- Q-column tiles (n_tile<8) only store rows
// m>=2048, so the 128 blocks with m_tile<16 && n_tile<8 computed a full
// 128x128x1024 MFMA tile and wrote NOTHING. New decoder:
//   id <  128: Q region,  m_tile = 16 + id/8  (16..31), n_tile = id%8  (0..7)
//   id >= 128: KV region, m_tile = (id-128)/16 (0..31), n_tile = 8 + (id-128)%16
// Epilogue predicates unchanged -> bit-identical results, 16.7% fewer FLOPs.
__global__ __launch_bounds__(256) void qkv_rhk_kernel(
    const ushort* __restrict__ Am, const ushort* __restrict__ Ah,
    const ushort* __restrict__ Bt,
    const float* __restrict__ rwb, const float* __restrict__ rrb,
    ushort* __restrict__ Qw, ushort* __restrict__ Qr,
    ushort* __restrict__ Kg, ushort* __restrict__ Vg,
    const ushort* __restrict__ Apos, const ushort* __restrict__ Brw,
    ushort* __restrict__ rhkT) {
    __shared__ ushort As[2 * 128 * 32];
    __shared__ ushort Bs[2 * 128 * 32];
    if (blockIdx.x < 640) {
        int id = blockIdx.x;
        int mt, nt;
        if (id < 128) { mt = 16 + (id >> 3); nt = id & 7; }
        else          { int rid = id - 128; mt = rid >> 4; nt = 8 + (rid & 15); }
        int m0 = mt * 128, n0 = nt * 128;
        const ushort* Aeff = (m0 < 2048) ? Am : (Ah - (size_t)2048 * DMODEL);
        GEMM_BODY_DMA_DB(Aeff, Bt, DMODEL)
        #pragma unroll
        for (int ni = 0; ni < 4; ++ni) {
            int e = n0 + wc * 64 + ni * 16 + fr;
            #pragma unroll
            for (int mi = 0; mi < 4; ++mi) {
                int rg = m0 + wr * 64 + mi * 16 + kq * 4;
                #pragma unroll
                for (int r = 0; r < 4; ++r) {
                    float v = acc[mi][ni][r];
                    int m = rg + r;
                    int b_ = m & 7, jr = m >> 3;
                    if (e < 1024) {
                        if (m >= 2048) {
                            int n_ = e >> 6, d_ = e & 63, i_ = jr - 256;
                            size_t qa = (((size_t)b_ * 16 + n_) * 256 + i_) * 64 + d_;
                            Qw[qa] = f2b(v + rwb[e]);
                            Qr[qa] = f2b(v + rrb[e]);
                        }
                    } else if (e < 2048) {
                        int e2 = e - 1024;
                        int n_ = e2 >> 6, d_ = e2 & 63;
                        Kg[(((size_t)b_ * 16 + n_) * 512 + jr) * 64 + d_] = f2b(v);
                    } else {
                        int e2 = e - 2048;
                        int n_ = e2 >> 6, d_ = e2 & 63;
                        Vg[(((size_t)b_ * 16 + n_) * 512 + jr) * 64 + d_] = f2b(v);
                    }
                }
            }
        }
    } else {
        int rid = blockIdx.x - 640;
        int m0 = (rid / 8) * 128, n0 = (rid % 8) * 128;
        GEMM_BODY_REG(Apos, Brw, DMODEL)
        #pragma unroll
        for (int ni = 0; ni < 4; ++ni) {
            int e = n0 + wc * 64 + ni * 16 + fr;
            int n_ = e >> 6, d_ = e & 63;
            #pragma unroll
            for (int mi = 0; mi < 4; ++mi) {
                int rg = m0 + wr * 64 + mi * 16 + kq * 4;
                #pragma unroll
                for (int r = 0; r < 4; ++r)
                    rhkT[((size_t)n_ * 512 + (rg + r)) * 64 + d_] = f2b(acc[mi][ni][r]);
            }
        }
    }
}

// BDfull per (b,n): Qr(256x64) @ rhkT_n(512x64)^T, rel-shift in epilogue.
// R25: tile (m0=0, n0=0) is fully dead (j = rr+i-255 < 0 for all i<=127,
// rr<=127 -> never written). Grid dim3(7,1,128) with a 7-entry decoder.
__global__ __launch_bounds__(256) void bd_gemm_kernel(
    const ushort* __restrict__ QrAll, const ushort* __restrict__ rhkT,
    ushort* __restrict__ BDs) {
    __shared__ ushort As[2 * 128 * 32];
    __shared__ ushort Bs[2 * 128 * 32];
    int batch = blockIdx.z;                    // b*16+n
    const ushort* A  = QrAll + (size_t)batch * (256 * 64);
    const ushort* Bt = rhkT + (size_t)(batch & 15) * (512 * 64);
    ushort* BDb = BDs + (size_t)batch * (256 * 512);
    int bx = blockIdx.x;
    int m0, n0;
    if (bx < 3) { m0 = 0;   n0 = (bx + 1) * 128; }
    else        { m0 = 128; n0 = (bx - 3) * 128; }
    GEMM_BODY_DMA_DB(A, Bt, 64)
    #pragma unroll
    for (int ni = 0; ni < 4; ++ni) {
        int rr = n0 + wc * 64 + ni * 16 + fr;
        #pragma unroll
        for (int mi = 0; mi < 4; ++mi) {
            int rg = m0 + wr * 64 + mi * 16 + kq * 4;
            #pragma unroll
            for (int r = 0; r < 4; ++r) {
                int i = rg + r;
                int j = rr + i - 255;
                if ((unsigned)j < 512u)
                    BDb[(size_t)i * 512 + j] = f2b(acc[mi][ni][r]);
            }
        }
    }
}

// ---------------- fused flash attention ----------------
__global__ __launch_bounds__(256) void fused_attn_kernel(
    const ushort* __restrict__ Qw, const ushort* __restrict__ Kg,
    const ushort* __restrict__ Vg, const ushort* __restrict__ BDs,
    ushort* __restrict__ vec) {
    __shared__ ushort Ks[64 * 72];
    __shared__ ushort Vt[64 * 72];
    __shared__ ushort Pl[4][16 * 72];
    const int qt = blockIdx.x, b = blockIdx.y, n = blockIdx.z;
    const int tid = threadIdx.x, wv = tid >> 6, lane = tid & 63;
    const int fr = lane & 15, kq = lane >> 4;
    const int q0 = qt * 64;
    const size_t bn = (size_t)b * 16 + n;
    const ushort* Qb  = Qw + bn * 256 * 64;
    const ushort* Kb  = Kg + bn * 512 * 64;
    const ushort* Vb  = Vg + bn * 512 * 64;
    const ushort* BDb = BDs + bn * 256 * 512;
    bf16x8 aq0, aq1;
    {
        const ushort* qp = Qb + (size_t)(q0 + wv * 16 + fr) * 64 + kq * 8;
        aq0 = *(const bf16x8*)qp;
        aq1 = *(const bf16x8*)(qp + 32);
    }
    f32x4 O[4] = {};
    float m_r[4], l_r[4];
    #pragma unroll
    for (int r = 0; r < 4; ++r) { m_r[r] = -INFINITY; l_r[r] = 0.0f; }
    const int NT = qt + 5;
    const int krow = tid >> 2, kseg = tid & 3;
    const int vrow = tid & 63, vseg0 = tid >> 6;
    for (int jt = 0; jt < NT; ++jt) {
        __syncthreads();
        {
            const ushort* src = Kb + (size_t)(jt * 64 + krow) * 64 + kseg * 16;
            *(float4*)&Ks[krow * 72 + kseg * 16]     = *(const float4*)src;
            *(float4*)&Ks[krow * 72 + kseg * 16 + 8] = *(const float4*)(src + 8);
        }
        #pragma unroll
        for (int it = 0; it < 2; ++it) {
            int seg = vseg0 + it * 4;
            const ushort* src = Vb + (size_t)(jt * 64 + vrow) * 64 + seg * 8;
            bf16x8 v = *(const bf16x8*)src;
            #pragma unroll
            for (int q = 0; q < 8; ++q)
                Vt[(seg * 8 + q) * 72 + vrow] = (ushort)v[q];
        }
        __syncthreads();
        f32x4 S[4] = {};
        #pragma unroll
        for (int cb = 0; cb < 4; ++cb) {
            const ushort* kp = &Ks[(cb * 16 + fr) * 72 + kq * 8];
            bf16x8 b0 = *(const bf16x8*)kp;
            bf16x8 b1 = *(const bf16x8*)(kp + 32);
            S[cb] = __builtin_amdgcn_mfma_f32_16x16x32_bf16(aq0, b0, S[cb], 0, 0, 0);
            S[cb] = __builtin_amdgcn_mfma_f32_16x16x32_bf16(aq1, b1, S[cb], 0, 0, 0);
        }
        #pragma unroll
        for (int cb = 0; cb < 4; ++cb) {
            int j = jt * 64 + cb * 16 + fr;
            #pragma unroll
            for (int r = 0; r < 4; ++r) {
                int i = q0 + wv * 16 + kq * 4 + r;
                float bd = b2f(BDb[(size_t)i * 512 + j]);
                float s = (S[cb][r] + bd) * 0.125f;
                S[cb][r] = (j <= i + 256) ? s : -1e30f;
            }
        }
        float sc[4];
        #pragma unroll
        for (int r = 0; r < 4; ++r) {
            float t = fmaxf(fmaxf(S[0][r], S[1][r]), fmaxf(S[2][r], S[3][r]));
            t = fmaxf(t, __shfl_xor(t, 1));
            t = fmaxf(t, __shfl_xor(t, 2));
            t = fmaxf(t, __shfl_xor(t, 4));
            t = fmaxf(t, __shfl_xor(t, 8));
            float mn = fmaxf(m_r[r], t);
            sc[r] = __expf(m_r[r] - mn);
            m_r[r] = mn;
        }
        float ts[4] = {0.0f, 0.0f, 0.0f, 0.0f};
        #pragma unroll
        for (int cb = 0; cb < 4; ++cb)
            #pragma unroll
            for (int r = 0; r < 4; ++r) {
                float p = __expf(S[cb][r] - m_r[r]);
                S[cb][r] = p;
                ts[r] += p;
            }
        #pragma unroll
        for (int r = 0; r < 4; ++r) {
            float t = ts[r];
            t += __shfl_xor(t, 1);
            t += __shfl_xor(t, 2);
            t += __shfl_xor(t, 4);
            t += __shfl_xor(t, 8);
            l_r[r] = l_r[r] * sc[r] + t;
            #pragma unroll
            for (int ob = 0; ob < 4; ++ob) O[ob][r] *= sc[r];
        }
        ushort* P = &Pl[wv][0];
        #pragma unroll
        for (int cb = 0; cb < 4; ++cb)
            #pragma unroll
            for (int r = 0; r < 4; ++r)
                P[(kq * 4 + r) * 72 + cb * 16 + fr] = f2b(S[cb][r]);
        asm volatile("s_waitcnt lgkmcnt(0)" ::: "memory");
        bf16x8 pa0 = *(const bf16x8*)&P[fr * 72 + kq * 8];
        bf16x8 pa1 = *(const bf16x8*)&P[fr * 72 + 32 + kq * 8];
        #pragma unroll
        for (int ob = 0; ob < 4; ++ob) {
            const ushort* vp = &Vt[(ob * 16 + fr) * 72 + kq * 8];
            bf16x8 v0 = *(const bf16x8*)vp;
            bf16x8 v1 = *(const bf16x8*)(vp + 32);
            O[ob] = __builtin_amdgcn_mfma_f32_16x16x32_bf16(pa0, v0, O[ob], 0, 0, 0);
            O[ob] = __builtin_amdgcn_mfma_f32_16x16x32_bf16(pa1, v1, O[ob], 0, 0, 0);
        }
    }
    #pragma unroll
    for (int r = 0; r < 4; ++r) {
        float inv = 1.0f / l_r[r];
        int i = q0 + wv * 16 + kq * 4 + r;
        size_t base = ((size_t)i * 8 + b) * 1024 + n * 64;
        #pragma unroll
        for (int ob = 0; ob < 4; ++ob)
            vec[base + ob * 16 + fr] = f2b(O[ob][r] * inv);
    }
}

// logits GEMM + fused per-token (max, sumexp) + fused tgt dot-products.
__global__ __launch_bounds__(256) void logits_lse_kernel(
    const ushort* __restrict__ A, const ushort* __restrict__ Bt,
    const float* __restrict__ ob, float* __restrict__ pmax, float* __restrict__ psum,
    const float* __restrict__ hf, const float* __restrict__ Wf,
    const int* __restrict__ target, float* __restrict__ tgtout) {
    __shared__ ushort As[128 * 32];
    __shared__ ushort Bs[128 * 32];
    __shared__ float redm[2][128], reds[2][128];
    if (blockIdx.x >= 4000) {
        int wv2 = threadIdx.x >> 6, lane2 = threadIdx.x & 63;
        int t = (blockIdx.x - 4000) * 4 + wv2;
        int row = target[t];
        const float* hp = hf + (size_t)t * DMODEL;
        const float* wp = Wf + (size_t)row * DMODEL;
        float s = 0.0f;
        for (int d = lane2; d < DMODEL; d += 64) s += hp[d] * wp[d];
        for (int o = 32; o > 0; o >>= 1) s += __shfl_down(s, o);
        if (lane2 == 0) tgtout[t] = s + ob[row];
        return;
    }
    int logical = xcd_swizzle(blockIdx.x, 4000);
    int bx = logical / 16;       // vocab tile (slow)
    int by = logical % 16;       // token tile (fast)
    int m0 = bx * 128;           // vocab
    int n0 = by * 128;           // tokens
    GEMM_BODY_DMA_SB(A, Bt, DMODEL)
    int t0 = n0;
    #pragma unroll
    for (int ni = 0; ni < 4; ++ni) {
        float vals[16];
        float vmax = -1e30f;
        #pragma unroll
        for (int mi = 0; mi < 4; ++mi) {
            int rg = m0 + wr * 64 + mi * 16 + kq * 4;
            float4 ob4 = *(const float4*)&ob[rg];
            float o4[4] = {ob4.x, ob4.y, ob4.z, ob4.w};
            #pragma unroll
            for (int r = 0; r < 4; ++r) {
                float v = acc[mi][ni][r] + o4[r];
                vals[mi * 4 + r] = v;
                vmax = fmaxf(vmax, v);
            }
        }
        vmax = fmaxf(vmax, __shfl_xor(vmax, 16));
        vmax = fmaxf(vmax, __shfl_xor(vmax, 32));
        float s = 0.0f;
        #pragma unroll
        for (int q = 0; q < 16; ++q) s += __expf(vals[q] - vmax);
        s += __shfl_xor(s, 16);
        s += __shfl_xor(s, 32);
        if (kq == 0) {
            redm[wr][wc * 64 + ni * 16 + fr] = vmax;
            reds[wr][wc * 64 + ni * 16 + fr] = s;
        }
    }
    __syncthreads();
    if (tid < 128) {
        float ma = redm[0][tid], mb = redm[1][tid];
        float m = fmaxf(ma, mb);
        float s = reds[0][tid] * __expf(ma - m) + reds[1][tid] * __expf(mb - m);
        pmax[(size_t)(t0 + tid) * VTILES + bx] = m;
        psum[(size_t)(t0 + tid) * VTILES + bx] = s;
    }
}

// h = LN(act(x0+x1+x2+x3) + h)*g + b, writes fp32 h and bf16 copy.
template<int RELU>
__global__ __launch_bounds__(256) void ln_combine4_kernel(const float* __restrict__ x0,
    const float* __restrict__ x1, const float* __restrict__ x2,
    const float* __restrict__ x3, float* __restrict__ h, const float* __restrict__ g,
    const float* __restrict__ bb, ushort* __restrict__ hb) {
    int t = blockIdx.x, tid = threadIdx.x;
    __shared__ float rs[256], rq[256];
    float v[4];
    float s = 0.0f, sq = 0.0f;
    for (int u = 0; u < 4; ++u) {
        int d = tid + u * 256;
        size_t idx = (size_t)t * DMODEL + d;
        float xx = (x0[idx] + x1[idx]) + (x2[idx] + x3[idx]);
        if (RELU) xx = fmaxf(xx, 0.0f);
        float val = xx + h[idx];
        v[u] = val; s += val; sq += val * val;
    }
    rs[tid] = s; rq[tid] = sq;
    __syncthreads();
    for (int st = 128; st > 0; st >>= 1) {
        if (tid < st) { rs[tid] += rs[tid + st]; rq[tid] += rq[tid + st]; }
        __syncthreads();
    }
    float mean = rs[0] * (1.0f / DMODEL);
    float var = rq[0] * (1.0f / DMODEL) - mean * mean;
    float r = rsqrtf(var + 1e-3f);
    for (int u = 0; u < 4; ++u) {
        int d = tid + u * 256;
        float o = (v[u] - mean) * r * g[d] + bb[d];
        h[(size_t)t * DMODEL + d] = o;
        hb[(size_t)t * DMODEL + d] = f2b(o);
    }
}

// ---------------- final loss pieces ----------------

// 512 blocks x 256 threads; wave wv handles token t = blk*4 + wv.
__global__ __launch_bounds__(256) void lse_kernel(const float* __restrict__ pmax,
    const float* __restrict__ psum, float* __restrict__ lse) {
    int wv = threadIdx.x >> 6, lane = threadIdx.x & 63;
    int t = blockIdx.x * 4 + wv;
    const float* pm = pmax + (size_t)t * VTILES;
    const float* ps = psum + (size_t)t * VTILES;
    float m = -1e30f;
    for (int c = lane; c < VTILES; c += 64) m = fmaxf(m, pm[c]);
    for (int o = 32; o > 0; o >>= 1) m = fmaxf(m, __shfl_xor(m, o));
    float s = 0.0f;
    for (int c = lane; c < VTILES; c += 64) s += ps[c] * expf(pm[c] - m);
    for (int o = 32; o > 0; o >>= 1) s += __shfl_xor(s, o);
    if (lane == 0) lse[t] = m + logf(s);
}

__global__ __launch_bounds__(256) void loss_kernel(const float* __restrict__ lse,
    const float* __restrict__ tgt, const float* __restrict__ vm, float* __restrict__ out) {
    __shared__ float red[256];
    int tid = threadIdx.x;
    float s = 0.0f;
    for (int t = tid; t < NTOK; t += 256) s += (lse[t] - tgt[t]) * vm[t];
    red[tid] = s;
    __syncthreads();
    for (int st = 128; st > 0; st >>= 1) {
        if (tid < st) red[tid] += red[tid + st];
        __syncthreads();
    }
    if (tid == 0) out[0] = red[0] * (1.0f / NTOK);
}

// ---------------- launch ----------------
extern "C" void kernel_launch(void* const* d_in, const int* in_sizes, int n_in,
                              void* d_out, int out_size, void* d_ws, size_t ws_size,
                              hipStream_t stream) {
    const int*   dec_inp   = (const int*)  d_in[0];
    const int*   target    = (const int*)  d_in[1];
    const float* valid     = (const float*)d_in[2];
    const float* mems      = (const float*)d_in[3];
    const float* vocab_emb = (const float*)d_in[4];
    const float* out_w     = (const float*)d_in[5];
    const float* out_b     = (const float*)d_in[6];
    const float* qkv_w     = (const float*)d_in[7];
    const float* r_w       = (const float*)d_in[8];
    const float* o_w       = (const float*)d_in[9];
    const float* ln1_g     = (const float*)d_in[10];
    const float* ln1_b     = (const float*)d_in[11];
    const float* ff_w1     = (const float*)d_in[12];
    const float* ff_b1     = (const float*)d_in[13];
    const float* ff_w2     = (const float*)d_in[14];
    const float* ff_b2     = (const float*)d_in[15];
    const float* ln2_g     = (const float*)d_in[16];
    const float* ln2_b     = (const float*)d_in[17];
    const float* r_w_bias  = (const float*)d_in[18];
    const float* r_r_bias  = (const float*)d_in[19];

    float* ws = (float*)d_ws;
    float*  h      = ws + O_H;
    ushort* hbf    = (ushort*)(ws + O_HBF);
    ushort* posbf  = (ushort*)(ws + O_POSBF);
    ushort* qkvt   = (ushort*)(ws + O_QKVT);
    ushort* rwt    = (ushort*)(ws + O_RWT);
    ushort* owt    = (ushort*)(ws + O_OWT);
    ushort* ffw1t  = (ushort*)(ws + O_FFW1T);
    ushort* ffw2t  = (ushort*)(ws + O_FFW2T);
    ushort* membf  = (ushort*)(ws + O_MEMBF);
    ushort* qwv    = (ushort*)(ws + O_QW);
    ushort* qrv    = (ushort*)(ws + O_QR);
    ushort* kg     = (ushort*)(ws + O_KG);
    ushort* vg     = (ushort*)(ws + O_VG);
    ushort* rhkT   = (ushort*)(ws + O_RHKT);
    ushort* vecbf  = (ushort*)(ws + O_VECBF);
    float*  tattn  = ws + O_TATTN;
    ushort* bds    = (ushort*)(ws + O_BDS);
    float*  owp0   = ws + O_BDS;
    float*  owp1   = ws + O_BDS + 2097152;
    float*  owp2   = ws + O_BDS + 4194304;
    float*  owp3   = ws + O_BDS + 6291456;
    ushort* t1bf   = (ushort*)(ws + O_T1BF);
    float*  t2     = ws + O_T2;
    float*  t2b    = ws + O_T2B;
    float*  ffp2   = tattn;
    float*  ffp3   = (float*)(ws + O_KG);
    ushort* outwbf = (ushort*)(ws + O_OUTWBF);
    float*  pmax   = ws + O_PMAX;
    float*  psum   = ws + O_PSUM;
    float*  lse    = ws + O_LSE;
    float*  tgt    = ws + O_TGT;

    prep_all_kernel<<<33280, 256, 0, stream>>>(
        qkv_w, r_w, o_w, ff_w1, ff_w2, qkvt, rwt, owt, ffw1t, ffw2t,
        dec_inp, vocab_emb, h, hbf, posbf, mems, membf);

    for (int l = 0; l < NLAYER; ++l) {
        // 640 live GEMM blocks (dead Q-region tiles removed) + 32 rhk
        qkv_rhk_kernel<<<672, 256, 0, stream>>>(
            membf + (size_t)l * 2097152, hbf,
            qkvt + (size_t)l * 3072 * DMODEL, r_w_bias, r_r_bias, qwv, qrv, kg, vg,
            posbf, rwt + (size_t)l * DMODEL * DMODEL, rhkT);
        // 7 live tiles per batch (dead (0,0) tile removed)
        bd_gemm_kernel<<<dim3(7, 1, 128), 256, 0, stream>>>(qrv, rhkT, bds);
        fused_attn_kernel<<<dim3(4, BSZ, NHEAD), 256, 0, stream>>>(qwv, kg, vg, bds, vecbf);
        gemm_splitk4_kernel<<<dim3(8, 16, 4), 256, 0, stream>>>(
            vecbf, owt + (size_t)l * DMODEL * DMODEL, nullptr,
            owp0, owp1, owp2, owp3, DMODEL, DMODEL);
        ln_combine4_kernel<0><<<NTOK, 256, 0, stream>>>(
            owp0, owp1, owp2, owp3, h, ln1_g + l * DMODEL, ln1_b + l * DMODEL, hbf);
        gemm_bf16_kernel<1, 1><<<dim3(32, 16), 256, 0, stream>>>(
            hbf, ffw1t + (size_t)l * DINNER * DMODEL, ff_b1 + (size_t)l * DINNER, t1bf, NTOK, DINNER, DMODEL);
        gemm_splitk4_kernel<<<dim3(8, 16, 4), 256, 0, stream>>>(
            t1bf, ffw2t + (size_t)l * DMODEL * DINNER, ff_b2 + (size_t)l * DMODEL,
            t2, t2b, ffp2, ffp3, DMODEL, DINNER);
        ln_combine4_kernel<1><<<NTOK, 256, 0, stream>>>(
            t2, t2b, ffp2, ffp3, h, ln2_g + l * DMODEL, ln2_b + l * DMODEL, hbf);
    }

    convert_bf16_kernel<<<32000, 256, 0, stream>>>(out_w, outwbf);
    logits_lse_kernel<<<4512, 256, 0, stream>>>(
        outwbf, hbf, out_b, pmax, psum, h, out_w, target, tgt);
    lse_kernel<<<512, 256, 0, stream>>>(pmax, psum, lse);
    loss_kernel<<<1, 256, 0, stream>>>(lse, tgt, valid, (float*)d_out);
}